// Round 1
// baseline (388.902 us; speedup 1.0000x reference)
//
#include <hip/hip_runtime.h>
#include <math.h>

// Problem constants
#define B_ 4
#define C_ 256
#define CO_ 256
#define H_ 64
#define W_ 64
#define HW_ 4096
#define KK_ 9   // 3x3 kernel positions
#define NCH_ 27 // 18 offset + 9 mask channels

// ---------------------------------------------------------------------------
// Kernel 1: init offmask with biases (offmask[b][ch][hw] = bias[ch])
// ---------------------------------------------------------------------------
__global__ void init_offmask(const float* __restrict__ b_off,
                             const float* __restrict__ b_mask,
                             float* __restrict__ offmask) {
    int i = blockIdx.x * 256 + threadIdx.x;
    if (i >= B_ * NCH_ * HW_) return;
    int ch = (i >> 12) % NCH_;
    offmask[i] = (ch < 18) ? b_off[ch] : b_mask[ch - 18];
}

// ---------------------------------------------------------------------------
// Kernel 2: fused offset+mask 3x3 conv, channel-split with fp32 atomics.
// grid = 512: bid -> cg(8 groups of 32 in-channels) x tile(16 of 16x16 px) x b(4)
// ---------------------------------------------------------------------------
__global__ void conv_offmask(const float* __restrict__ x,
                             const float* __restrict__ w_off,
                             const float* __restrict__ w_mask,
                             float* __restrict__ offmask) {
    __shared__ float xt[18 * 18];
    __shared__ float wt[NCH_ * 12];  // 9 weights padded to 12 for aligned float4
    const int t = threadIdx.x;
    const int cg = blockIdx.x & 7;
    const int tile = (blockIdx.x >> 3) & 15;
    const int b = blockIdx.x >> 7;
    const int ty0 = (tile >> 2) << 4, tx0 = (tile & 3) << 4;
    const int ty = t >> 4, tx = t & 15;

    float acc[NCH_];
#pragma unroll
    for (int ch = 0; ch < NCH_; ++ch) acc[ch] = 0.f;

    const int c_beg = cg << 5;
    for (int c = c_beg; c < c_beg + 32; ++c) {
        __syncthreads();
        // stage 18x18 zero-padded x tile for channel c
        for (int e = t; e < 324; e += 256) {
            int r = e / 18, cc = e - r * 18;
            int yy = ty0 - 1 + r, xx = tx0 - 1 + cc;
            float v = 0.f;
            if (yy >= 0 && yy < H_ && xx >= 0 && xx < W_)
                v = x[(((size_t)(b << 8) + c) << 12) + (yy << 6) + xx];
            xt[e] = v;
        }
        // stage 27x9 weights for channel c (padded rows of 12)
        for (int e = t; e < NCH_ * 9; e += 256) {
            int ch = e / 9, j = e - ch * 9;
            float wv = (ch < 18) ? w_off[(size_t)(ch * C_ + c) * 9 + j]
                                 : w_mask[(size_t)((ch - 18) * C_ + c) * 9 + j];
            wt[ch * 12 + j] = wv;
        }
        __syncthreads();

        float xv[9];
#pragma unroll
        for (int i = 0; i < 3; ++i)
#pragma unroll
            for (int j = 0; j < 3; ++j)
                xv[i * 3 + j] = xt[(ty + i) * 18 + tx + j];

#pragma unroll
        for (int ch = 0; ch < NCH_; ++ch) {
            float4 w0 = *(const float4*)&wt[ch * 12];
            float4 w1 = *(const float4*)&wt[ch * 12 + 4];
            float w8 = wt[ch * 12 + 8];
            float s = acc[ch];
            s = fmaf(xv[0], w0.x, s); s = fmaf(xv[1], w0.y, s);
            s = fmaf(xv[2], w0.z, s); s = fmaf(xv[3], w0.w, s);
            s = fmaf(xv[4], w1.x, s); s = fmaf(xv[5], w1.y, s);
            s = fmaf(xv[6], w1.z, s); s = fmaf(xv[7], w1.w, s);
            s = fmaf(xv[8], w8, s);
            acc[ch] = s;
        }
    }

    const int py = ty0 + ty, px = tx0 + tx;
#pragma unroll
    for (int ch = 0; ch < NCH_; ++ch)
        atomicAdd(&offmask[(((size_t)b * NCH_ + ch) << 12) + (py << 6) + px], acc[ch]);
}

// ---------------------------------------------------------------------------
// Kernel 3: transpose x NCHW -> NHWC (xT[b][hw][c])
// ---------------------------------------------------------------------------
__global__ void transpose_x(const float* __restrict__ x, float* __restrict__ xT) {
    __shared__ float tile[32][33];
    const int t = threadIdx.x;
    const int tx = t & 31, ty = t >> 5;  // ty 0..7
    const int b = blockIdx.x >> 10;
    const int rem = blockIdx.x & 1023;
    const int c0 = (rem >> 7) << 5;
    const int hw0 = (rem & 127) << 5;
    const float* xb = x + ((size_t)b << 20);
    float* xTb = xT + ((size_t)b << 20);
#pragma unroll
    for (int r = 0; r < 4; ++r) {
        int row = ty + (r << 3);
        tile[row][tx] = xb[((size_t)(c0 + row) << 12) + hw0 + tx];
    }
    __syncthreads();
#pragma unroll
    for (int r = 0; r < 4; ++r) {
        int row = ty + (r << 3);
        xTb[((size_t)(hw0 + row) << 8) + c0 + tx] = tile[tx][row];
    }
}

// ---------------------------------------------------------------------------
// Kernel 4: transpose w_dcn [o][c][k] -> wT[k][c][o]
// grid = 64 blocks: 8 o-groups x 8 c-groups, 32x32x9 each
// ---------------------------------------------------------------------------
__global__ void transpose_w(const float* __restrict__ w_dcn, float* __restrict__ wT) {
    __shared__ float lw[32 * 289];  // [o][ck] with +1 row pad
    const int t = threadIdx.x;
    const int o0 = (blockIdx.x >> 3) << 5;
    const int c0 = (blockIdx.x & 7) << 5;
#pragma unroll
    for (int r = 0; r < 36; ++r) {
        int f = t + (r << 8);  // 0..9215
        int o = f / 288, ck = f - o * 288;
        lw[o * 289 + ck] = w_dcn[(size_t)(o0 + o) * 2304 + c0 * 9 + ck];
    }
    __syncthreads();
#pragma unroll
    for (int r = 0; r < 36; ++r) {
        int f = t + (r << 8);
        int o = f & 31, kc = f >> 5;      // kc 0..287
        int k = kc >> 5, c = kc & 31;     // 9 x 32
        wT[((size_t)((k << 8) + c0 + c) << 8) + o0 + o] = lw[o * 289 + c * 9 + k];
    }
}

// ---------------------------------------------------------------------------
// Kernel 5: main fused deformable-sample + contraction.
// grid = 512: b = bid & 3 (XCD-batch affinity), 32-pixel tile = bid >> 2.
// Block: 256 thr; thread owns 4 out-channels x 8 pixels (fp32 acc).
// Loop over k(9) x c-chunk(8x32): stage w[32c][256o] + val[32c][32p] in LDS.
// ---------------------------------------------------------------------------
__global__ void dcn_main(const float* __restrict__ xT,
                         const float* __restrict__ offmask,
                         const float* __restrict__ wT,
                         const float* __restrict__ b_dcn,
                         float* __restrict__ out) {
    __shared__ float4 cw[288];   // per (k,p): 4 bilinear weights * mask
    __shared__ int4 coff[288];   // per (k,p): 4 corner element offsets (NHWC)
    __shared__ float wlds[32 * 256];
    __shared__ float vlds[32 * 32];

    const int t = threadIdx.x;
    const int b = blockIdx.x & 3;
    const int pix0 = (blockIdx.x >> 2) << 5;
    const float* xb = xT + ((size_t)b << 20);
    const float* omb = offmask + (((size_t)b * NCH_) << 12);

    // phase 0: coords for 9 k-positions x 32 pixels
    for (int e = t; e < 288; e += 256) {
        int k = e >> 5, p = e & 31;
        int pix = pix0 + p;
        int hh = pix >> 6, ww = pix & 63;
        float dy = omb[((size_t)(2 * k) << 12) + pix];
        float dx = omb[((size_t)(2 * k + 1) << 12) + pix];
        float ml = omb[((size_t)(18 + k) << 12) + pix];
        float m = 1.f / (1.f + __expf(-ml));
        float py = (float)(hh - 1 + (k / 3)) + dy;
        float px = (float)(ww - 1 + (k % 3)) + dx;
        float fy0 = floorf(py), fx0 = floorf(px);
        float ay = py - fy0, ax = px - fx0;
        bool y0v = (fy0 >= 0.f) && (fy0 <= 63.f);
        bool y1v = (fy0 >= -1.f) && (fy0 <= 62.f);
        bool x0v = (fx0 >= 0.f) && (fx0 <= 63.f);
        bool x1v = (fx0 >= -1.f) && (fx0 <= 62.f);
        int y0 = (int)fy0, x0 = (int)fx0;
        int iy0 = min(max(y0, 0), 63), iy1 = min(max(y0 + 1, 0), 63);
        int ix0 = min(max(x0, 0), 63), ix1 = min(max(x0 + 1, 0), 63);
        float w00 = (y0v && x0v) ? m * (1.f - ay) * (1.f - ax) : 0.f;
        float w01 = (y0v && x1v) ? m * (1.f - ay) * ax : 0.f;
        float w10 = (y1v && x0v) ? m * ay * (1.f - ax) : 0.f;
        float w11 = (y1v && x1v) ? m * ay * ax : 0.f;
        cw[e] = make_float4(w00, w01, w10, w11);
        coff[e] = make_int4(((iy0 << 6) + ix0) << 8, ((iy0 << 6) + ix1) << 8,
                            ((iy1 << 6) + ix0) << 8, ((iy1 << 6) + ix1) << 8);
    }
    __syncthreads();

    float acc[4][8];
#pragma unroll
    for (int i = 0; i < 4; ++i)
#pragma unroll
        for (int j = 0; j < 8; ++j) acc[i][j] = 0.f;

    const int to = t >> 2, tp = t & 3;

    for (int k = 0; k < KK_; ++k) {
        for (int cc = 0; cc < 8; ++cc) {
            // stage w chunk: wT[k][cc*32 .. +32][0..256] contiguous 8192 floats
            const float4* wsrc = (const float4*)(wT + (((size_t)(k << 8) + (cc << 5)) << 8));
#pragma unroll
            for (int r = 0; r < 8; ++r)
                ((float4*)wlds)[t + (r << 8)] = wsrc[t + (r << 8)];
            // stage val chunk: 32c x 32p, coalesced gather over c, XOR-swizzled store
#pragma unroll
            for (int r = 0; r < 4; ++r) {
                int e = (r << 8) + t;
                int c = e & 31, p = e >> 5;
                float4 w4 = cw[(k << 5) + p];
                int4 o4 = coff[(k << 5) + p];
                int cg = (cc << 5) + c;
                float v = w4.x * xb[o4.x + cg] + w4.y * xb[o4.y + cg] +
                          w4.z * xb[o4.z + cg] + w4.w * xb[o4.w + cg];
                vlds[(c << 5) + (p ^ ((c & 3) << 3))] = v;
            }
            __syncthreads();
#pragma unroll
            for (int c = 0; c < 32; ++c) {
                float4 wv4 = *(const float4*)&wlds[(c << 8) + (to << 2)];
                int vg = (c << 5) + ((tp ^ (c & 3)) << 3);
                float4 va = *(const float4*)&vlds[vg];
                float4 vb = *(const float4*)&vlds[vg + 4];
                float wvs[4] = {wv4.x, wv4.y, wv4.z, wv4.w};
                float vvs[8] = {va.x, va.y, va.z, va.w, vb.x, vb.y, vb.z, vb.w};
#pragma unroll
                for (int i = 0; i < 4; ++i)
#pragma unroll
                    for (int j = 0; j < 8; ++j)
                        acc[i][j] = fmaf(wvs[i], vvs[j], acc[i][j]);
            }
            __syncthreads();
        }
    }

#pragma unroll
    for (int i = 0; i < 4; ++i) {
        int o = (to << 2) + i;
        float bo = b_dcn[o];
        float* dst = out + ((((size_t)(b << 8)) + o) << 12) + pix0 + (tp << 3);
        float4 r0 = make_float4(acc[i][0] + bo, acc[i][1] + bo, acc[i][2] + bo, acc[i][3] + bo);
        float4 r1 = make_float4(acc[i][4] + bo, acc[i][5] + bo, acc[i][6] + bo, acc[i][7] + bo);
        *(float4*)dst = r0;
        *(float4*)(dst + 4) = r1;
    }
}

// ---------------------------------------------------------------------------
extern "C" void kernel_launch(void* const* d_in, const int* in_sizes, int n_in,
                              void* d_out, int out_size, void* d_ws, size_t ws_size,
                              hipStream_t stream) {
    const float* x      = (const float*)d_in[0];
    const float* w_off  = (const float*)d_in[1];
    const float* b_off  = (const float*)d_in[2];
    const float* w_mask = (const float*)d_in[3];
    const float* b_mask = (const float*)d_in[4];
    const float* w_dcn  = (const float*)d_in[5];
    const float* b_dcn  = (const float*)d_in[6];
    float* out = (float*)d_out;

    float* ws = (float*)d_ws;
    float* xT      = ws;                          // 4*4096*256   = 4,194,304 f
    float* offmask = xT + (size_t)B_ * HW_ * C_;  // 4*27*4096    =   442,368 f
    float* wT      = offmask + (size_t)B_ * NCH_ * HW_;  // 9*256*256 = 589,824 f
    // total ~20.9 MB of d_ws

    init_offmask<<<dim3((B_ * NCH_ * HW_ + 255) / 256), dim3(256), 0, stream>>>(b_off, b_mask, offmask);
    conv_offmask<<<dim3(512), dim3(256), 0, stream>>>(x, w_off, w_mask, offmask);
    transpose_x<<<dim3(4096), dim3(256), 0, stream>>>(x, xT);
    transpose_w<<<dim3(64), dim3(256), 0, stream>>>(w_dcn, wT);
    dcn_main<<<dim3(512), dim3(256), 0, stream>>>(xT, offmask, wT, b_dcn, out);
}

// Round 2
// 197.214 us; speedup vs baseline: 1.9720x; 1.9720x over previous
//
#include <hip/hip_runtime.h>
#include <math.h>

// Problem constants
#define B_ 4
#define C_ 256
#define CO_ 256
#define H_ 64
#define W_ 64
#define HW_ 4096
#define KK_ 9   // 3x3 kernel positions
#define NCH_ 27 // 18 offset + 9 mask channels

typedef __attribute__((ext_vector_type(8))) short bf16x8;
typedef __attribute__((ext_vector_type(4))) float f32x4;

__device__ inline unsigned short f32_to_bf16(float f) {
    unsigned int u = __float_as_uint(f);
    unsigned int r = (u + 0x7FFFu + ((u >> 16) & 1u)) >> 16;  // RNE
    return (unsigned short)r;
}

// ---------------------------------------------------------------------------
// Kernel 1: init offmask with biases (offmask[b][ch][hw] = bias[ch])
// ---------------------------------------------------------------------------
__global__ void init_offmask(const float* __restrict__ b_off,
                             const float* __restrict__ b_mask,
                             float* __restrict__ offmask) {
    int i = blockIdx.x * 256 + threadIdx.x;
    if (i >= B_ * NCH_ * HW_) return;
    int ch = (i >> 12) % NCH_;
    offmask[i] = (ch < 18) ? b_off[ch] : b_mask[ch - 18];
}

// ---------------------------------------------------------------------------
// Kernel 2: fused offset+mask 3x3 conv, channel-split with fp32 atomics.
// ---------------------------------------------------------------------------
__global__ void conv_offmask(const float* __restrict__ x,
                             const float* __restrict__ w_off,
                             const float* __restrict__ w_mask,
                             float* __restrict__ offmask) {
    __shared__ float xt[18 * 18];
    __shared__ float wt[NCH_ * 12];
    const int t = threadIdx.x;
    const int cg = blockIdx.x & 7;
    const int tile = (blockIdx.x >> 3) & 15;
    const int b = blockIdx.x >> 7;
    const int ty0 = (tile >> 2) << 4, tx0 = (tile & 3) << 4;
    const int ty = t >> 4, tx = t & 15;

    float acc[NCH_];
#pragma unroll
    for (int ch = 0; ch < NCH_; ++ch) acc[ch] = 0.f;

    const int c_beg = cg << 5;
    for (int c = c_beg; c < c_beg + 32; ++c) {
        __syncthreads();
        for (int e = t; e < 324; e += 256) {
            int r = e / 18, cc = e - r * 18;
            int yy = ty0 - 1 + r, xx = tx0 - 1 + cc;
            float v = 0.f;
            if (yy >= 0 && yy < H_ && xx >= 0 && xx < W_)
                v = x[(((size_t)(b << 8) + c) << 12) + (yy << 6) + xx];
            xt[e] = v;
        }
        for (int e = t; e < NCH_ * 9; e += 256) {
            int ch = e / 9, j = e - ch * 9;
            float wv = (ch < 18) ? w_off[(size_t)(ch * C_ + c) * 9 + j]
                                 : w_mask[(size_t)((ch - 18) * C_ + c) * 9 + j];
            wt[ch * 12 + j] = wv;
        }
        __syncthreads();

        float xv[9];
#pragma unroll
        for (int i = 0; i < 3; ++i)
#pragma unroll
            for (int j = 0; j < 3; ++j)
                xv[i * 3 + j] = xt[(ty + i) * 18 + tx + j];

#pragma unroll
        for (int ch = 0; ch < NCH_; ++ch) {
            float4 w0 = *(const float4*)&wt[ch * 12];
            float4 w1 = *(const float4*)&wt[ch * 12 + 4];
            float w8 = wt[ch * 12 + 8];
            float s = acc[ch];
            s = fmaf(xv[0], w0.x, s); s = fmaf(xv[1], w0.y, s);
            s = fmaf(xv[2], w0.z, s); s = fmaf(xv[3], w0.w, s);
            s = fmaf(xv[4], w1.x, s); s = fmaf(xv[5], w1.y, s);
            s = fmaf(xv[6], w1.z, s); s = fmaf(xv[7], w1.w, s);
            s = fmaf(xv[8], w8, s);
            acc[ch] = s;
        }
    }

    const int py = ty0 + ty, px = tx0 + tx;
#pragma unroll
    for (int ch = 0; ch < NCH_; ++ch)
        atomicAdd(&offmask[(((size_t)b * NCH_ + ch) << 12) + (py << 6) + px], acc[ch]);
}

// ---------------------------------------------------------------------------
// Kernel 3: transpose x NCHW -> NHWC (xT[b][hw][c])
// ---------------------------------------------------------------------------
__global__ void transpose_x(const float* __restrict__ x, float* __restrict__ xT) {
    __shared__ float tile[32][33];
    const int t = threadIdx.x;
    const int tx = t & 31, ty = t >> 5;
    const int b = blockIdx.x >> 10;
    const int rem = blockIdx.x & 1023;
    const int c0 = (rem >> 7) << 5;
    const int hw0 = (rem & 127) << 5;
    const float* xb = x + ((size_t)b << 20);
    float* xTb = xT + ((size_t)b << 20);
#pragma unroll
    for (int r = 0; r < 4; ++r) {
        int row = ty + (r << 3);
        tile[row][tx] = xb[((size_t)(c0 + row) << 12) + hw0 + tx];
    }
    __syncthreads();
#pragma unroll
    for (int r = 0; r < 4; ++r) {
        int row = ty + (r << 3);
        xTb[((size_t)(hw0 + row) << 8) + c0 + tx] = tile[tx][row];
    }
}

// ---------------------------------------------------------------------------
// Kernel 4: prep w_dcn [o][c][k] f32 -> wTs bf16, per-chunk [o][ck] rows of 64
// with 16B-slot XOR swizzle pre-applied (so linear global_load_lds + swizzled
// ds_read_b128 is correct). chunk = k*4+cc covers c in [cc*64, cc*64+64).
// element pos within chunk: o*64 + (((ck>>3) ^ (o&7))<<3) + (ck&7)
// ---------------------------------------------------------------------------
__global__ void prep_w(const float* __restrict__ w_dcn, unsigned short* __restrict__ wTs) {
    const int chunk = blockIdx.x;           // 0..35
    const int k = chunk >> 2, cc = chunk & 3;
    const int t = threadIdx.x;
    for (int e = t; e < 16384; e += 256) {
        int o = e >> 6, ck = e & 63;
        float v = w_dcn[((size_t)o * C_ + (cc * 64 + ck)) * 9 + k];
        int pos = (o << 6) + ((((ck >> 3) ^ (o & 7)) << 3)) + (ck & 7);
        wTs[(size_t)chunk * 16384 + pos] = f32_to_bf16(v);
    }
}

// ---------------------------------------------------------------------------
// Kernel 5: main deformable-sample + bf16 MFMA contraction.
// grid 256: b=(bid&7)>>1 (XCD pair per batch), tile=(bid>>3)+((bid&1)<<5).
// block 512 thr = 8 waves (4 o-rows x 2 p-cols), wave = 64o x 32p.
// K loop: 36 chunks of 64 ck; double-buffered LDS; T14 load/finish split.
// ---------------------------------------------------------------------------
__global__ __launch_bounds__(512, 2) void dcn_main(
    const float* __restrict__ xT, const float* __restrict__ offmask,
    const unsigned short* __restrict__ wTs, const float* __restrict__ b_dcn,
    float* __restrict__ out) {
    __shared__ float4 cw[576];                       //  9216 B
    __shared__ int4 coff[576];                       //  9216 B
    __shared__ alignas(16) unsigned short wbuf[2][16384];  // 65536 B
    __shared__ alignas(16) unsigned short vbuf[2][4096];   // 16384 B

    const int t = threadIdx.x;
    const int bid = blockIdx.x;
    const int b = (bid & 7) >> 1;
    const int tile = (bid >> 3) + ((bid & 1) << 5);
    const int pix0 = tile << 6;
    const float* xb = xT + ((size_t)b << 20);
    const float* omb = offmask + (((size_t)b * NCH_) << 12);

    // ---- phase 0: bilinear weights (mask folded) + corner offsets, 9k x 64p
    for (int e = t; e < 576; e += 512) {
        int k = e >> 6, p = e & 63;
        int pix = pix0 + p;
        int hh = pix >> 6, ww = pix & 63;
        float dy = omb[((size_t)(2 * k) << 12) + pix];
        float dx = omb[((size_t)(2 * k + 1) << 12) + pix];
        float ml = omb[((size_t)(18 + k) << 12) + pix];
        float m = 1.f / (1.f + __expf(-ml));
        float py = (float)(hh - 1 + (k / 3)) + dy;
        float px = (float)(ww - 1 + (k % 3)) + dx;
        float fy0 = floorf(py), fx0 = floorf(px);
        float ay = py - fy0, ax = px - fx0;
        bool y0v = (fy0 >= 0.f) && (fy0 <= 63.f);
        bool y1v = (fy0 >= -1.f) && (fy0 <= 62.f);
        bool x0v = (fx0 >= 0.f) && (fx0 <= 63.f);
        bool x1v = (fx0 >= -1.f) && (fx0 <= 62.f);
        int y0 = (int)fy0, x0 = (int)fx0;
        int iy0 = min(max(y0, 0), 63), iy1 = min(max(y0 + 1, 0), 63);
        int ix0 = min(max(x0, 0), 63), ix1 = min(max(x0 + 1, 0), 63);
        float w00 = (y0v && x0v) ? m * (1.f - ay) * (1.f - ax) : 0.f;
        float w01 = (y0v && x1v) ? m * (1.f - ay) * ax : 0.f;
        float w10 = (y1v && x0v) ? m * ay * (1.f - ax) : 0.f;
        float w11 = (y1v && x1v) ? m * ay * ax : 0.f;
        cw[e] = make_float4(w00, w01, w10, w11);
        coff[e] = make_int4(((iy0 << 6) + ix0) << 8, ((iy0 << 6) + ix1) << 8,
                            ((iy1 << 6) + ix0) << 8, ((iy1 << 6) + ix1) << 8);
    }

    const int cpair = t & 31, pg = t >> 5;   // producer mapping: 2 c x 4 p
    const int wid = t >> 6, lane = t & 63;
    const int wo = wid >> 1, wp = wid & 1;
    const int m16 = lane & 15, kg = lane >> 4;

    // stage w chunk into wbuf[buf] (linear; source pre-swizzled)
    auto stage_w = [&](int chunk, int buf) {
#pragma unroll
        for (int r = 0; r < 4; ++r) {
            int off16 = (r << 9) + t;   // 16B units, 0..2047
            const unsigned short* g = wTs + ((size_t)chunk << 14) + (off16 << 3);
            unsigned short* l = &wbuf[buf][off16 << 3];
            __builtin_amdgcn_global_load_lds(
                (const __attribute__((address_space(1))) unsigned int*)g,
                (__attribute__((address_space(3))) unsigned int*)l, 16, 0, 0);
        }
    };

    float2 smp[4][4];
    // issue the 16 gather loads for chunk (k,cc) into regs
    auto produce_load = [&](int chunk) {
        int k = chunk >> 2, cc = chunk & 3;
        int cb = (cc << 6) + (cpair << 1);
#pragma unroll
        for (int i = 0; i < 4; ++i) {
            int p = (pg << 2) + i;
            int4 o4 = coff[(k << 6) + p];
            smp[i][0] = *(const float2*)(xb + o4.x + cb);
            smp[i][1] = *(const float2*)(xb + o4.y + cb);
            smp[i][2] = *(const float2*)(xb + o4.z + cb);
            smp[i][3] = *(const float2*)(xb + o4.w + cb);
        }
    };
    // combine + pack + swizzled ds_write into vbuf[buf]
    auto produce_finish = [&](int chunk, int buf) {
        int k = chunk >> 2;
#pragma unroll
        for (int i = 0; i < 4; ++i) {
            int p = (pg << 2) + i;
            float4 w4 = cw[(k << 6) + p];
            float lo = w4.x * smp[i][0].x + w4.y * smp[i][1].x +
                       w4.z * smp[i][2].x + w4.w * smp[i][3].x;
            float hi = w4.x * smp[i][0].y + w4.y * smp[i][1].y +
                       w4.z * smp[i][2].y + w4.w * smp[i][3].y;
            unsigned int pk = (unsigned int)f32_to_bf16(lo) |
                              ((unsigned int)f32_to_bf16(hi) << 16);
            int u32i = (p << 5) + (((cpair >> 2) ^ (p & 7)) << 2) + (cpair & 3);
            ((unsigned int*)vbuf[buf])[u32i] = pk;
        }
    };

    f32x4 acc[4][2] = {};

    __syncthreads();            // coords visible
    // prologue: chunk 0
    stage_w(0, 0);
    produce_load(0);
    produce_finish(0, 0);
    __syncthreads();

    for (int chunk = 0; chunk < 36; ++chunk) {
        int cur = chunk & 1, nxt = cur ^ 1;
        if (chunk < 35) {
            stage_w(chunk + 1, nxt);
            produce_load(chunk + 1);
        }
        // MFMA over chunk from wbuf[cur]/vbuf[cur]
#pragma unroll
        for (int ks = 0; ks < 2; ++ks) {
            int s = (ks << 2) + kg;
            bf16x8 aF[4], bF[2];
#pragma unroll
            for (int i = 0; i < 4; ++i) {
                int o = (wo << 6) + (i << 4) + m16;
                aF[i] = *(const bf16x8*)&wbuf[cur][(o << 6) + ((s ^ (o & 7)) << 3)];
            }
#pragma unroll
            for (int j = 0; j < 2; ++j) {
                int p = (wp << 5) + (j << 4) + m16;
                bF[j] = *(const bf16x8*)&vbuf[cur][(p << 6) + ((s ^ (p & 7)) << 3)];
            }
#pragma unroll
            for (int i = 0; i < 4; ++i)
#pragma unroll
                for (int j = 0; j < 2; ++j)
                    acc[i][j] = __builtin_amdgcn_mfma_f32_16x16x32_bf16(
                        aF[i], bF[j], acc[i][j], 0, 0, 0);
        }
        if (chunk < 35) produce_finish(chunk + 1, nxt);
        __syncthreads();
    }

    // epilogue: C/D layout col=lane&15, row=(lane>>4)*4+r
#pragma unroll
    for (int i = 0; i < 4; ++i) {
        int ob = (wo << 6) + (i << 4) + (kg << 2);
#pragma unroll
        for (int j = 0; j < 2; ++j) {
            int p = pix0 + (wp << 5) + (j << 4) + m16;
#pragma unroll
            for (int r = 0; r < 4; ++r) {
                int oo = ob + r;
                out[(((size_t)(b << 8) + oo) << 12) + p] = acc[i][j][r] + b_dcn[oo];
            }
        }
    }
}

// ---------------------------------------------------------------------------
extern "C" void kernel_launch(void* const* d_in, const int* in_sizes, int n_in,
                              void* d_out, int out_size, void* d_ws, size_t ws_size,
                              hipStream_t stream) {
    const float* x      = (const float*)d_in[0];
    const float* w_off  = (const float*)d_in[1];
    const float* b_off  = (const float*)d_in[2];
    const float* w_mask = (const float*)d_in[3];
    const float* b_mask = (const float*)d_in[4];
    const float* w_dcn  = (const float*)d_in[5];
    const float* b_dcn  = (const float*)d_in[6];
    float* out = (float*)d_out;

    float* ws = (float*)d_ws;
    float* xT      = ws;                                  // 4,194,304 f32
    float* offmask = xT + (size_t)B_ * HW_ * C_;          //   442,368 f32
    unsigned short* wTs = (unsigned short*)(offmask + (size_t)B_ * NCH_ * HW_); // 589,824 bf16

    init_offmask<<<dim3(1728), dim3(256), 0, stream>>>(b_off, b_mask, offmask);
    conv_offmask<<<dim3(512), dim3(256), 0, stream>>>(x, w_off, w_mask, offmask);
    transpose_x<<<dim3(4096), dim3(256), 0, stream>>>(x, xT);
    prep_w<<<dim3(36), dim3(256), 0, stream>>>(w_dcn, wTs);
    dcn_main<<<dim3(256), dim3(512), 0, stream>>>(xT, offmask, wTs, b_dcn, out);
}

// Round 3
// 128.738 us; speedup vs baseline: 3.0209x; 1.5319x over previous
//
#include <hip/hip_runtime.h>
#include <math.h>

// Problem constants
#define B_ 4
#define C_ 256
#define CO_ 256
#define H_ 64
#define W_ 64
#define HW_ 4096
#define KK_ 9   // 3x3 kernel positions
#define NCH_ 27 // 18 offset + 9 mask channels

typedef __attribute__((ext_vector_type(8))) short bf16x8;
typedef __attribute__((ext_vector_type(4))) float f32x4;

__device__ inline unsigned short f32_to_bf16(float f) {
    unsigned int u = __float_as_uint(f);
    unsigned int r = (u + 0x7FFFu + ((u >> 16) & 1u)) >> 16;  // RNE
    return (unsigned short)r;
}

// ---------------------------------------------------------------------------
// Kernel 1: transpose x NCHW -> NHWC (xT[b][hw][c])
// ---------------------------------------------------------------------------
__global__ void transpose_x(const float* __restrict__ x, float* __restrict__ xT) {
    __shared__ float tile[32][33];
    const int t = threadIdx.x;
    const int tx = t & 31, ty = t >> 5;
    const int b = blockIdx.x >> 10;
    const int rem = blockIdx.x & 1023;
    const int c0 = (rem >> 7) << 5;
    const int hw0 = (rem & 127) << 5;
    const float* xb = x + ((size_t)b << 20);
    float* xTb = xT + ((size_t)b << 20);
#pragma unroll
    for (int r = 0; r < 4; ++r) {
        int row = ty + (r << 3);
        tile[row][tx] = xb[((size_t)(c0 + row) << 12) + hw0 + tx];
    }
    __syncthreads();
#pragma unroll
    for (int r = 0; r < 4; ++r) {
        int row = ty + (r << 3);
        xTb[((size_t)(hw0 + row) << 8) + c0 + tx] = tile[tx][row];
    }
}

// ---------------------------------------------------------------------------
// Kernel 2: pack all weights to bf16, pre-swizzled for linear global_load_lds
// + swizzled ds_read_b128. chunk = k*4+cc covers c in [cc*64, cc*64+64).
// element pos within chunk row o: (o<<6) + (((ck>>3) ^ (o&7))<<3) + (ck&7)
// blocks 0..35: w_dcn -> wTs [chunk][256][64]
// blocks 36..71: w_off/w_mask (+5 zero rows) -> wCs [chunk][32][64]
// ---------------------------------------------------------------------------
__global__ void prep_weights(const float* __restrict__ w_dcn,
                             const float* __restrict__ w_off,
                             const float* __restrict__ w_mask,
                             unsigned short* __restrict__ wTs,
                             unsigned short* __restrict__ wCs) {
    const int t = threadIdx.x;
    if (blockIdx.x < 36) {
        const int chunk = blockIdx.x;
        const int k = chunk >> 2, cc = chunk & 3;
        for (int e = t; e < 16384; e += 256) {
            int o = e >> 6, ck = e & 63;
            float v = w_dcn[((size_t)o * C_ + (cc * 64 + ck)) * 9 + k];
            int pos = (o << 6) + (((ck >> 3) ^ (o & 7)) << 3) + (ck & 7);
            wTs[(size_t)chunk * 16384 + pos] = f32_to_bf16(v);
        }
    } else {
        const int chunk = blockIdx.x - 36;
        const int k = chunk >> 2, cc = chunk & 3;
        for (int e = t; e < 2048; e += 256) {
            int o = e >> 6, ck = e & 63;
            int c = (cc << 6) + ck;
            float v = 0.f;
            if (o < 18) v = w_off[((size_t)o * C_ + c) * 9 + k];
            else if (o < NCH_) v = w_mask[((size_t)(o - 18) * C_ + c) * 9 + k];
            int pos = (o << 6) + (((ck >> 3) ^ (o & 7)) << 3) + (ck & 7);
            wCs[(size_t)chunk * 2048 + pos] = f32_to_bf16(v);
        }
    }
}

// ---------------------------------------------------------------------------
// Kernel 3: offset+mask 3x3 conv via bf16 MFMA.
// out[32ch][64p] = sum_{ck} wC[ch][ck] * im2col(xT)[ck][p], per (b, row hh).
// grid 256: b=(bid&7)>>1, hh=(bid>>3)+((bid&1)<<5). 256 thr = 4 waves,
// wave w: pixels [16w,16w+16), 32 channels, acc[2] f32x4.
// ---------------------------------------------------------------------------
__global__ __launch_bounds__(256) void conv_mfma(
    const float* __restrict__ xT, const unsigned short* __restrict__ wCs,
    const float* __restrict__ b_off, const float* __restrict__ b_mask,
    float* __restrict__ offmask) {
    __shared__ alignas(16) unsigned short wlds[2][2048];   //  8 KB
    __shared__ alignas(16) unsigned short xlds[2][4096];   // 16 KB
    const int t = threadIdx.x;
    const int bid = blockIdx.x;
    const int b = (bid & 7) >> 1;
    const int hh = (bid >> 3) + ((bid & 1) << 5);
    const float* xb = xT + ((size_t)b << 20);

    auto stage_w = [&](int chunk, int buf) {
        const unsigned short* g = wCs + ((size_t)chunk << 11) + (t << 3);
        __builtin_amdgcn_global_load_lds(
            (const __attribute__((address_space(1))) unsigned int*)g,
            (__attribute__((address_space(3))) unsigned int*)&wlds[buf][t << 3], 16, 0, 0);
    };

    auto stage_x = [&](int chunk, int buf) {
        int k = chunk >> 2, cc = chunk & 3;
        int ki = k / 3, kj = k % 3;
        int py = hh + ki - 1;
#pragma unroll
        for (int r = 0; r < 2; ++r) {
            int slot = (r << 8) + t;
            int p = slot >> 3, cs = slot & 7;
            int px = p + kj - 1;
            float4 v0 = make_float4(0.f, 0.f, 0.f, 0.f), v1 = v0;
            if (py >= 0 && py < H_ && px >= 0 && px < W_) {
                const float* src = xb + (((size_t)((py << 6) + px)) << 8) + (cc << 6) + (cs << 3);
                v0 = *(const float4*)src;
                v1 = *(const float4*)(src + 4);
            }
            union { bf16x8 v; unsigned short u[8]; } pk;
            pk.u[0] = f32_to_bf16(v0.x); pk.u[1] = f32_to_bf16(v0.y);
            pk.u[2] = f32_to_bf16(v0.z); pk.u[3] = f32_to_bf16(v0.w);
            pk.u[4] = f32_to_bf16(v1.x); pk.u[5] = f32_to_bf16(v1.y);
            pk.u[6] = f32_to_bf16(v1.z); pk.u[7] = f32_to_bf16(v1.w);
            *(bf16x8*)&xlds[buf][(p << 6) + ((cs ^ (p & 7)) << 3)] = pk.v;
        }
    };

    const int wid = t >> 6, lane = t & 63;
    const int m16 = lane & 15, kg = lane >> 4;
    f32x4 acc[2] = {};

    stage_w(0, 0);
    stage_x(0, 0);
    __syncthreads();

    for (int chunk = 0; chunk < 36; ++chunk) {
        int cur = chunk & 1, nxt = cur ^ 1;
        if (chunk < 35) { stage_w(chunk + 1, nxt); stage_x(chunk + 1, nxt); }
#pragma unroll
        for (int ks = 0; ks < 2; ++ks) {
            int s = (ks << 2) + kg;
            int sw = (s ^ (m16 & 7)) << 3;
            bf16x8 a0 = *(const bf16x8*)&wlds[cur][(m16 << 6) + sw];
            bf16x8 a1 = *(const bf16x8*)&wlds[cur][((m16 + 16) << 6) + sw];
            int p = (wid << 4) + m16;
            bf16x8 bf = *(const bf16x8*)&xlds[cur][(p << 6) + ((s ^ (p & 7)) << 3)];
            acc[0] = __builtin_amdgcn_mfma_f32_16x16x32_bf16(a0, bf, acc[0], 0, 0, 0);
            acc[1] = __builtin_amdgcn_mfma_f32_16x16x32_bf16(a1, bf, acc[1], 0, 0, 0);
        }
        __syncthreads();
    }

    // C/D layout: col=lane&15 (pixel), row=(lane>>4)*4+r (+16 per frag) (channel)
    const int ww = (wid << 4) + m16;
#pragma unroll
    for (int i = 0; i < 2; ++i)
#pragma unroll
        for (int r = 0; r < 4; ++r) {
            int ch = (i << 4) + (kg << 2) + r;
            if (ch < NCH_) {
                float bias = (ch < 18) ? b_off[ch] : b_mask[ch - 18];
                offmask[(((size_t)b * NCH_ + ch) << 12) + (hh << 6) + ww] = acc[i][r] + bias;
            }
        }
}

// ---------------------------------------------------------------------------
// Kernel 4: main deformable-sample + bf16 MFMA contraction.
// grid 256: b=(bid&7)>>1 (XCD pair per batch), tile=(bid>>3)+((bid&1)<<5).
// block 512 thr = 8 waves (4 o-rows x 2 p-cols), wave = 64o x 32p.
// K loop: 36 chunks of 64 ck; double-buffered LDS; T14 load/finish split.
// ---------------------------------------------------------------------------
__global__ __launch_bounds__(512, 2) void dcn_main(
    const float* __restrict__ xT, const float* __restrict__ offmask,
    const unsigned short* __restrict__ wTs, const float* __restrict__ b_dcn,
    float* __restrict__ out) {
    __shared__ float4 cw[576];                       //  9216 B
    __shared__ int4 coff[576];                       //  9216 B
    __shared__ alignas(16) unsigned short wbuf[2][16384];  // 65536 B
    __shared__ alignas(16) unsigned short vbuf[2][4096];   // 16384 B

    const int t = threadIdx.x;
    const int bid = blockIdx.x;
    const int b = (bid & 7) >> 1;
    const int tile = (bid >> 3) + ((bid & 1) << 5);
    const int pix0 = tile << 6;
    const float* xb = xT + ((size_t)b << 20);
    const float* omb = offmask + (((size_t)b * NCH_) << 12);

    // ---- phase 0: bilinear weights (mask folded) + corner offsets, 9k x 64p
    for (int e = t; e < 576; e += 512) {
        int k = e >> 6, p = e & 63;
        int pix = pix0 + p;
        int hh = pix >> 6, ww = pix & 63;
        float dy = omb[((size_t)(2 * k) << 12) + pix];
        float dx = omb[((size_t)(2 * k + 1) << 12) + pix];
        float ml = omb[((size_t)(18 + k) << 12) + pix];
        float m = 1.f / (1.f + __expf(-ml));
        float py = (float)(hh - 1 + (k / 3)) + dy;
        float px = (float)(ww - 1 + (k % 3)) + dx;
        float fy0 = floorf(py), fx0 = floorf(px);
        float ay = py - fy0, ax = px - fx0;
        bool y0v = (fy0 >= 0.f) && (fy0 <= 63.f);
        bool y1v = (fy0 >= -1.f) && (fy0 <= 62.f);
        bool x0v = (fx0 >= 0.f) && (fx0 <= 63.f);
        bool x1v = (fx0 >= -1.f) && (fx0 <= 62.f);
        int y0 = (int)fy0, x0 = (int)fx0;
        int iy0 = min(max(y0, 0), 63), iy1 = min(max(y0 + 1, 0), 63);
        int ix0 = min(max(x0, 0), 63), ix1 = min(max(x0 + 1, 0), 63);
        float w00 = (y0v && x0v) ? m * (1.f - ay) * (1.f - ax) : 0.f;
        float w01 = (y0v && x1v) ? m * (1.f - ay) * ax : 0.f;
        float w10 = (y1v && x0v) ? m * ay * (1.f - ax) : 0.f;
        float w11 = (y1v && x1v) ? m * ay * ax : 0.f;
        cw[e] = make_float4(w00, w01, w10, w11);
        coff[e] = make_int4(((iy0 << 6) + ix0) << 8, ((iy0 << 6) + ix1) << 8,
                            ((iy1 << 6) + ix0) << 8, ((iy1 << 6) + ix1) << 8);
    }

    const int cpair = t & 31, pg = t >> 5;   // producer mapping: 2 c x 4 p
    const int wid = t >> 6, lane = t & 63;
    const int wo = wid >> 1, wp = wid & 1;
    const int m16 = lane & 15, kg = lane >> 4;

    auto stage_w = [&](int chunk, int buf) {
#pragma unroll
        for (int r = 0; r < 4; ++r) {
            int off16 = (r << 9) + t;   // 16B units, 0..2047
            const unsigned short* g = wTs + ((size_t)chunk << 14) + (off16 << 3);
            unsigned short* l = &wbuf[buf][off16 << 3];
            __builtin_amdgcn_global_load_lds(
                (const __attribute__((address_space(1))) unsigned int*)g,
                (__attribute__((address_space(3))) unsigned int*)l, 16, 0, 0);
        }
    };

    float2 smp[4][4];
    auto produce_load = [&](int chunk) {
        int k = chunk >> 2, cc = chunk & 3;
        int cb = (cc << 6) + (cpair << 1);
#pragma unroll
        for (int i = 0; i < 4; ++i) {
            int p = (pg << 2) + i;
            int4 o4 = coff[(k << 6) + p];
            smp[i][0] = *(const float2*)(xb + o4.x + cb);
            smp[i][1] = *(const float2*)(xb + o4.y + cb);
            smp[i][2] = *(const float2*)(xb + o4.z + cb);
            smp[i][3] = *(const float2*)(xb + o4.w + cb);
        }
    };
    auto produce_finish = [&](int chunk, int buf) {
        int k = chunk >> 2;
#pragma unroll
        for (int i = 0; i < 4; ++i) {
            int p = (pg << 2) + i;
            float4 w4 = cw[(k << 6) + p];
            float lo = w4.x * smp[i][0].x + w4.y * smp[i][1].x +
                       w4.z * smp[i][2].x + w4.w * smp[i][3].x;
            float hi = w4.x * smp[i][0].y + w4.y * smp[i][1].y +
                       w4.z * smp[i][2].y + w4.w * smp[i][3].y;
            unsigned int pk = (unsigned int)f32_to_bf16(lo) |
                              ((unsigned int)f32_to_bf16(hi) << 16);
            int u32i = (p << 5) + (((cpair >> 2) ^ (p & 7)) << 2) + (cpair & 3);
            ((unsigned int*)vbuf[buf])[u32i] = pk;
        }
    };

    f32x4 acc[4][2] = {};

    __syncthreads();            // coords visible
    stage_w(0, 0);
    produce_load(0);
    produce_finish(0, 0);
    __syncthreads();

    for (int chunk = 0; chunk < 36; ++chunk) {
        int cur = chunk & 1, nxt = cur ^ 1;
        if (chunk < 35) {
            stage_w(chunk + 1, nxt);
            produce_load(chunk + 1);
        }
#pragma unroll
        for (int ks = 0; ks < 2; ++ks) {
            int s = (ks << 2) + kg;
            bf16x8 aF[4], bF[2];
#pragma unroll
            for (int i = 0; i < 4; ++i) {
                int o = (wo << 6) + (i << 4) + m16;
                aF[i] = *(const bf16x8*)&wbuf[cur][(o << 6) + ((s ^ (o & 7)) << 3)];
            }
#pragma unroll
            for (int j = 0; j < 2; ++j) {
                int p = (wp << 5) + (j << 4) + m16;
                bF[j] = *(const bf16x8*)&vbuf[cur][(p << 6) + ((s ^ (p & 7)) << 3)];
            }
#pragma unroll
            for (int i = 0; i < 4; ++i)
#pragma unroll
                for (int j = 0; j < 2; ++j)
                    acc[i][j] = __builtin_amdgcn_mfma_f32_16x16x32_bf16(
                        aF[i], bF[j], acc[i][j], 0, 0, 0);
        }
        if (chunk < 35) produce_finish(chunk + 1, nxt);
        __syncthreads();
    }

    // epilogue: C/D layout col=lane&15, row=(lane>>4)*4+r
#pragma unroll
    for (int i = 0; i < 4; ++i) {
        int ob = (wo << 6) + (i << 4) + (kg << 2);
#pragma unroll
        for (int j = 0; j < 2; ++j) {
            int p = pix0 + (wp << 5) + (j << 4) + m16;
#pragma unroll
            for (int r = 0; r < 4; ++r) {
                int oo = ob + r;
                out[(((size_t)(b << 8) + oo) << 12) + p] = acc[i][j][r] + b_dcn[oo];
            }
        }
    }
}

// ---------------------------------------------------------------------------
extern "C" void kernel_launch(void* const* d_in, const int* in_sizes, int n_in,
                              void* d_out, int out_size, void* d_ws, size_t ws_size,
                              hipStream_t stream) {
    const float* x      = (const float*)d_in[0];
    const float* w_off  = (const float*)d_in[1];
    const float* b_off  = (const float*)d_in[2];
    const float* w_mask = (const float*)d_in[3];
    const float* b_mask = (const float*)d_in[4];
    const float* w_dcn  = (const float*)d_in[5];
    const float* b_dcn  = (const float*)d_in[6];
    float* out = (float*)d_out;

    float* ws = (float*)d_ws;
    float* xT      = ws;                                  // 4,194,304 f32
    float* offmask = xT + (size_t)B_ * HW_ * C_;          //   442,368 f32
    unsigned short* wTs = (unsigned short*)(offmask + (size_t)B_ * NCH_ * HW_); // 589,824 bf16
    unsigned short* wCs = wTs + (size_t)36 * 16384;       //    73,728 bf16

    transpose_x<<<dim3(4096), dim3(256), 0, stream>>>(x, xT);
    prep_weights<<<dim3(72), dim3(256), 0, stream>>>(w_dcn, w_off, w_mask, wTs, wCs);
    conv_mfma<<<dim3(256), dim3(256), 0, stream>>>(xT, wCs, b_off, b_mask, offmask);
    dcn_main<<<dim3(256), dim3(512), 0, stream>>>(xT, offmask, wTs, b_dcn, out);
}

// Round 4
// 105.763 us; speedup vs baseline: 3.6771x; 1.2172x over previous
//
#include <hip/hip_runtime.h>
#include <math.h>

// Problem constants
#define B_ 4
#define C_ 256
#define CO_ 256
#define H_ 64
#define W_ 64
#define HW_ 4096
#define KK_ 9   // 3x3 kernel positions
#define NCH_ 27 // 18 offset + 9 mask channels

typedef __attribute__((ext_vector_type(8))) short bf16x8;
typedef __attribute__((ext_vector_type(4))) float f32x4;

__device__ inline unsigned short f32_to_bf16(float f) {
    unsigned int u = __float_as_uint(f);
    unsigned int r = (u + 0x7FFFu + ((u >> 16) & 1u)) >> 16;  // RNE
    return (unsigned short)r;
}

// ---------------------------------------------------------------------------
// Kernel 1: transpose x NCHW -> NHWC (xT[b][hw][c])
// ---------------------------------------------------------------------------
__global__ void transpose_x(const float* __restrict__ x, float* __restrict__ xT) {
    __shared__ float tile[32][33];
    const int t = threadIdx.x;
    const int tx = t & 31, ty = t >> 5;
    const int b = blockIdx.x >> 10;
    const int rem = blockIdx.x & 1023;
    const int c0 = (rem >> 7) << 5;
    const int hw0 = (rem & 127) << 5;
    const float* xb = x + ((size_t)b << 20);
    float* xTb = xT + ((size_t)b << 20);
#pragma unroll
    for (int r = 0; r < 4; ++r) {
        int row = ty + (r << 3);
        tile[row][tx] = xb[((size_t)(c0 + row) << 12) + hw0 + tx];
    }
    __syncthreads();
#pragma unroll
    for (int r = 0; r < 4; ++r) {
        int row = ty + (r << 3);
        xTb[((size_t)(hw0 + row) << 8) + c0 + tx] = tile[tx][row];
    }
}

// ---------------------------------------------------------------------------
// Kernel 2: pack all weights to bf16, pre-swizzled. Coalesced: one block per
// output row o (or channel ch), contiguous 2304-float read staged in LDS,
// scatter bf16 to the 36 chunks. chunk = k*4 + (c>>6); within-chunk
// pos = (o<<6) + (((ck>>3) ^ (o&7))<<3) + (ck&7), ck = c&63.
// blocks 0..255: w_dcn -> wTs [chunk][256][64]
// blocks 256..287: w_off/w_mask (+5 zero rows) -> wCs [chunk][32][64]
// ---------------------------------------------------------------------------
__global__ void prep_weights(const float* __restrict__ w_dcn,
                             const float* __restrict__ w_off,
                             const float* __restrict__ w_mask,
                             unsigned short* __restrict__ wTs,
                             unsigned short* __restrict__ wCs) {
    __shared__ float lw[2304];
    const int t = threadIdx.x;
    if (blockIdx.x < 256) {
        const int o = blockIdx.x;
        for (int e = t; e < 2304; e += 256) lw[e] = w_dcn[(size_t)o * 2304 + e];
        __syncthreads();
        for (int e = t; e < 2304; e += 256) {
            int k = e >> 8, c = e & 255;
            int chunk = (k << 2) + (c >> 6), ck = c & 63;
            int pos = (o << 6) + (((ck >> 3) ^ (o & 7)) << 3) + (ck & 7);
            wTs[(size_t)chunk * 16384 + pos] = f32_to_bf16(lw[c * 9 + k]);
        }
    } else {
        const int ch = blockIdx.x - 256;  // 0..31
        const float* src = (ch < 18) ? w_off + (size_t)ch * 2304
                         : (ch < NCH_) ? w_mask + (size_t)(ch - 18) * 2304
                         : nullptr;
        for (int e = t; e < 2304; e += 256) lw[e] = src ? src[e] : 0.f;
        __syncthreads();
        for (int e = t; e < 2304; e += 256) {
            int k = e >> 8, c = e & 255;
            int chunk = (k << 2) + (c >> 6), ck = c & 63;
            int pos = (ch << 6) + (((ck >> 3) ^ (ch & 7)) << 3) + (ck & 7);
            wCs[(size_t)chunk * 2048 + pos] = f32_to_bf16(lw[c * 9 + k]);
        }
    }
}

// ---------------------------------------------------------------------------
// Kernel 3: offset+mask 3x3 conv via bf16 MFMA, 32 pixels per block.
// grid 512 (2 blocks/CU): b=(bid&7)>>1, ph=bid&1, hh=bid>>3.
// 256 thr = 4 waves: wc=wid>>1 (16-ch group), wp=wid&1 (16-p group), acc f32x4.
// ---------------------------------------------------------------------------
__global__ __launch_bounds__(256, 2) void conv_mfma(
    const float* __restrict__ xT, const unsigned short* __restrict__ wCs,
    const float* __restrict__ b_off, const float* __restrict__ b_mask,
    float* __restrict__ offmask) {
    __shared__ alignas(16) unsigned short wlds[2][2048];   //  8 KB
    __shared__ alignas(16) unsigned short xlds[2][2048];   //  8 KB
    const int t = threadIdx.x;
    const int bid = blockIdx.x;
    const int b = (bid & 7) >> 1;
    const int ph = bid & 1;
    const int hh = bid >> 3;
    const float* xb = xT + ((size_t)b << 20);

    auto stage_w = [&](int chunk, int buf) {
        const unsigned short* g = wCs + ((size_t)chunk << 11) + (t << 3);
        __builtin_amdgcn_global_load_lds(
            (const __attribute__((address_space(1))) unsigned int*)g,
            (__attribute__((address_space(3))) unsigned int*)&wlds[buf][t << 3], 16, 0, 0);
    };

    auto stage_x = [&](int chunk, int buf) {
        int k = chunk >> 2, cc = chunk & 3;
        int ki = k / 3, kj = k % 3;
        int py = hh + ki - 1;
        int p = t >> 3, cs = t & 7;           // 32 p x 8 c-slots = 256
        int px = (ph << 5) + p + kj - 1;
        float4 v0 = make_float4(0.f, 0.f, 0.f, 0.f), v1 = v0;
        if (py >= 0 && py < H_ && px >= 0 && px < W_) {
            const float* src = xb + (((size_t)((py << 6) + px)) << 8) + (cc << 6) + (cs << 3);
            v0 = *(const float4*)src;
            v1 = *(const float4*)(src + 4);
        }
        union { bf16x8 v; unsigned short u[8]; } pk;
        pk.u[0] = f32_to_bf16(v0.x); pk.u[1] = f32_to_bf16(v0.y);
        pk.u[2] = f32_to_bf16(v0.z); pk.u[3] = f32_to_bf16(v0.w);
        pk.u[4] = f32_to_bf16(v1.x); pk.u[5] = f32_to_bf16(v1.y);
        pk.u[6] = f32_to_bf16(v1.z); pk.u[7] = f32_to_bf16(v1.w);
        *(bf16x8*)&xlds[buf][(p << 6) + ((cs ^ (p & 7)) << 3)] = pk.v;
    };

    const int wid = t >> 6, lane = t & 63;
    const int wc = wid >> 1, wp = wid & 1;
    const int m16 = lane & 15, kg = lane >> 4;
    f32x4 acc = {};

    stage_w(0, 0);
    stage_x(0, 0);
    __syncthreads();

    for (int chunk = 0; chunk < 36; ++chunk) {
        int cur = chunk & 1, nxt = cur ^ 1;
        if (chunk < 35) { stage_w(chunk + 1, nxt); stage_x(chunk + 1, nxt); }
#pragma unroll
        for (int ks = 0; ks < 2; ++ks) {
            int s = (ks << 2) + kg;
            int o = (wc << 4) + m16;
            bf16x8 a = *(const bf16x8*)&wlds[cur][(o << 6) + ((s ^ (o & 7)) << 3)];
            int p = (wp << 4) + m16;
            bf16x8 bf = *(const bf16x8*)&xlds[cur][(p << 6) + ((s ^ (p & 7)) << 3)];
            acc = __builtin_amdgcn_mfma_f32_16x16x32_bf16(a, bf, acc, 0, 0, 0);
        }
        __syncthreads();
    }

    // C/D layout: col=lane&15 (pixel), row=(lane>>4)*4+r (channel within 16)
    const int pix = (hh << 6) + (ph << 5) + (wp << 4) + m16;
#pragma unroll
    for (int r = 0; r < 4; ++r) {
        int ch = (wc << 4) + (kg << 2) + r;
        if (ch < NCH_) {
            float bias = (ch < 18) ? b_off[ch] : b_mask[ch - 18];
            offmask[(((size_t)b * NCH_ + ch) << 12) + pix] = acc[r] + bias;
        }
    }
}

// ---------------------------------------------------------------------------
// Kernel 4: main deformable-sample + bf16 MFMA contraction, 32 pixels/block.
// grid 512 (2 blocks/CU): b=(bid&7)>>1, tile=(bid>>3)+((bid&1)<<6), pix0=tile<<5.
// 512 thr = 8 waves (4 o-rows x 2 p-cols), wave = 64o x 16p, acc[4] f32x4.
// 36 chunks of 64 ck; double-buffered LDS; T14 load/finish split.
// LDS: 4608 + 2304 + 65536 + 8192 = 80640 B -> 2 blocks/CU.
// ---------------------------------------------------------------------------
__global__ __launch_bounds__(512, 4) void dcn_main(
    const float* __restrict__ xT, const float* __restrict__ offmask,
    const unsigned short* __restrict__ wTs, const float* __restrict__ b_dcn,
    float* __restrict__ out) {
    __shared__ float4 cw[288];                              //  4608 B
    __shared__ ushort4 coff[288];                           //  2304 B
    __shared__ alignas(16) unsigned short wbuf[2][16384];   // 65536 B
    __shared__ alignas(16) unsigned short vbuf[2][2048];    //  8192 B

    const int t = threadIdx.x;
    const int bid = blockIdx.x;
    const int b = (bid & 7) >> 1;
    const int tile = (bid >> 3) + ((bid & 1) << 6);   // 0..127
    const int pix0 = tile << 5;
    const float* xb = xT + ((size_t)b << 20);
    const float* omb = offmask + (((size_t)b * NCH_) << 12);

    // ---- phase 0: bilinear weights (mask folded) + corner pix indices, 9k x 32p
    if (t < 288) {
        int k = t >> 5, p = t & 31;
        int pix = pix0 + p;
        int hh = pix >> 6, ww = pix & 63;
        float dy = omb[((size_t)(2 * k) << 12) + pix];
        float dx = omb[((size_t)(2 * k + 1) << 12) + pix];
        float ml = omb[((size_t)(18 + k) << 12) + pix];
        float m = 1.f / (1.f + __expf(-ml));
        float py = (float)(hh - 1 + (k / 3)) + dy;
        float px = (float)(ww - 1 + (k % 3)) + dx;
        float fy0 = floorf(py), fx0 = floorf(px);
        float ay = py - fy0, ax = px - fx0;
        bool y0v = (fy0 >= 0.f) && (fy0 <= 63.f);
        bool y1v = (fy0 >= -1.f) && (fy0 <= 62.f);
        bool x0v = (fx0 >= 0.f) && (fx0 <= 63.f);
        bool x1v = (fx0 >= -1.f) && (fx0 <= 62.f);
        int y0 = (int)fy0, x0 = (int)fx0;
        int iy0 = min(max(y0, 0), 63), iy1 = min(max(y0 + 1, 0), 63);
        int ix0 = min(max(x0, 0), 63), ix1 = min(max(x0 + 1, 0), 63);
        float w00 = (y0v && x0v) ? m * (1.f - ay) * (1.f - ax) : 0.f;
        float w01 = (y0v && x1v) ? m * (1.f - ay) * ax : 0.f;
        float w10 = (y1v && x0v) ? m * ay * (1.f - ax) : 0.f;
        float w11 = (y1v && x1v) ? m * ay * ax : 0.f;
        cw[t] = make_float4(w00, w01, w10, w11);
        coff[t] = make_ushort4((unsigned short)((iy0 << 6) + ix0),
                               (unsigned short)((iy0 << 6) + ix1),
                               (unsigned short)((iy1 << 6) + ix0),
                               (unsigned short)((iy1 << 6) + ix1));
    }

    const int cpair = t & 31, pg = t >> 5;   // producer: 32 c-pairs x 16 p-groups
    const int wid = t >> 6, lane = t & 63;
    const int wo = wid >> 1, wp = wid & 1;
    const int m16 = lane & 15, kg = lane >> 4;

    auto stage_w = [&](int chunk, int buf) {
#pragma unroll
        for (int r = 0; r < 4; ++r) {
            int off16 = (r << 9) + t;   // 16B units, 0..2047
            const unsigned short* g = wTs + ((size_t)chunk << 14) + (off16 << 3);
            unsigned short* l = &wbuf[buf][off16 << 3];
            __builtin_amdgcn_global_load_lds(
                (const __attribute__((address_space(1))) unsigned int*)g,
                (__attribute__((address_space(3))) unsigned int*)l, 16, 0, 0);
        }
    };

    float2 smp[2][4];
    auto produce_load = [&](int chunk) {
        int k = chunk >> 2, cc = chunk & 3;
        int cb = (cc << 6) + (cpair << 1);
#pragma unroll
        for (int i = 0; i < 2; ++i) {
            int p = (pg << 1) + i;
            ushort4 o4 = coff[(k << 5) + p];
            smp[i][0] = *(const float2*)(xb + ((int)o4.x << 8) + cb);
            smp[i][1] = *(const float2*)(xb + ((int)o4.y << 8) + cb);
            smp[i][2] = *(const float2*)(xb + ((int)o4.z << 8) + cb);
            smp[i][3] = *(const float2*)(xb + ((int)o4.w << 8) + cb);
        }
    };
    auto produce_finish = [&](int chunk, int buf) {
        int k = chunk >> 2;
#pragma unroll
        for (int i = 0; i < 2; ++i) {
            int p = (pg << 1) + i;
            float4 w4 = cw[(k << 5) + p];
            float lo = w4.x * smp[i][0].x + w4.y * smp[i][1].x +
                       w4.z * smp[i][2].x + w4.w * smp[i][3].x;
            float hi = w4.x * smp[i][0].y + w4.y * smp[i][1].y +
                       w4.z * smp[i][2].y + w4.w * smp[i][3].y;
            unsigned int pk = (unsigned int)f32_to_bf16(lo) |
                              ((unsigned int)f32_to_bf16(hi) << 16);
            int u32i = (p << 5) + (((cpair >> 2) ^ (p & 7)) << 2) + (cpair & 3);
            ((unsigned int*)vbuf[buf])[u32i] = pk;
        }
    };

    f32x4 acc[4] = {};

    __syncthreads();            // coords visible
    stage_w(0, 0);
    produce_load(0);
    produce_finish(0, 0);
    __syncthreads();

    for (int chunk = 0; chunk < 36; ++chunk) {
        int cur = chunk & 1, nxt = cur ^ 1;
        if (chunk < 35) {
            stage_w(chunk + 1, nxt);
            produce_load(chunk + 1);
        }
#pragma unroll
        for (int ks = 0; ks < 2; ++ks) {
            int s = (ks << 2) + kg;
            bf16x8 aF[4], bF;
#pragma unroll
            for (int i = 0; i < 4; ++i) {
                int o = (wo << 6) + (i << 4) + m16;
                aF[i] = *(const bf16x8*)&wbuf[cur][(o << 6) + ((s ^ (o & 7)) << 3)];
            }
            {
                int p = (wp << 4) + m16;
                bF = *(const bf16x8*)&vbuf[cur][(p << 6) + ((s ^ (p & 7)) << 3)];
            }
#pragma unroll
            for (int i = 0; i < 4; ++i)
                acc[i] = __builtin_amdgcn_mfma_f32_16x16x32_bf16(aF[i], bF, acc[i], 0, 0, 0);
        }
        if (chunk < 35) produce_finish(chunk + 1, nxt);
        __syncthreads();
    }

    // epilogue: C/D layout col=lane&15 (pixel), row=(lane>>4)*4+r (o within 16)
#pragma unroll
    for (int i = 0; i < 4; ++i) {
        int ob = (wo << 6) + (i << 4) + (kg << 2);
        int p = pix0 + (wp << 4) + m16;
#pragma unroll
        for (int r = 0; r < 4; ++r) {
            int oo = ob + r;
            out[(((size_t)(b << 8) + oo) << 12) + p] = acc[i][r] + b_dcn[oo];
        }
    }
}

// ---------------------------------------------------------------------------
extern "C" void kernel_launch(void* const* d_in, const int* in_sizes, int n_in,
                              void* d_out, int out_size, void* d_ws, size_t ws_size,
                              hipStream_t stream) {
    const float* x      = (const float*)d_in[0];
    const float* w_off  = (const float*)d_in[1];
    const float* b_off  = (const float*)d_in[2];
    const float* w_mask = (const float*)d_in[3];
    const float* b_mask = (const float*)d_in[4];
    const float* w_dcn  = (const float*)d_in[5];
    const float* b_dcn  = (const float*)d_in[6];
    float* out = (float*)d_out;

    float* ws = (float*)d_ws;
    float* xT      = ws;                                  // 4,194,304 f32
    float* offmask = xT + (size_t)B_ * HW_ * C_;          //   442,368 f32
    unsigned short* wTs = (unsigned short*)(offmask + (size_t)B_ * NCH_ * HW_); // 589,824 bf16
    unsigned short* wCs = wTs + (size_t)36 * 16384;       //    73,728 bf16

    transpose_x<<<dim3(4096), dim3(256), 0, stream>>>(x, xT);
    prep_weights<<<dim3(288), dim3(256), 0, stream>>>(w_dcn, w_off, w_mask, wTs, wCs);
    conv_mfma<<<dim3(512), dim3(256), 0, stream>>>(xT, wCs, b_off, b_mask, offmask);
    dcn_main<<<dim3(512), dim3(512), 0, stream>>>(xT, offmask, wTs, b_dcn, out);
}

// Round 7
// 105.640 us; speedup vs baseline: 3.6814x; 1.0012x over previous
//
#include <hip/hip_runtime.h>
#include <math.h>

// Problem constants
#define B_ 4
#define C_ 256
#define CO_ 256
#define H_ 64
#define W_ 64
#define HW_ 4096
#define KK_ 9   // 3x3 kernel positions
#define NCH_ 27 // 18 offset + 9 mask channels

typedef __attribute__((ext_vector_type(8))) short bf16x8;
typedef __attribute__((ext_vector_type(4))) float f32x4;

__device__ inline unsigned short f32_to_bf16(float f) {
    unsigned int u = __float_as_uint(f);
    unsigned int r = (u + 0x7FFFu + ((u >> 16) & 1u)) >> 16;  // RNE
    return (unsigned short)r;
}

// ---------------------------------------------------------------------------
// Kernel 1: transpose x NCHW -> NHWC (xT[b][hw][c])
// ---------------------------------------------------------------------------
__global__ void transpose_x(const float* __restrict__ x, float* __restrict__ xT) {
    __shared__ float tile[32][33];
    const int t = threadIdx.x;
    const int tx = t & 31, ty = t >> 5;
    const int b = blockIdx.x >> 10;
    const int rem = blockIdx.x & 1023;
    const int c0 = (rem >> 7) << 5;
    const int hw0 = (rem & 127) << 5;
    const float* xb = x + ((size_t)b << 20);
    float* xTb = xT + ((size_t)b << 20);
#pragma unroll
    for (int r = 0; r < 4; ++r) {
        int row = ty + (r << 3);
        tile[row][tx] = xb[((size_t)(c0 + row) << 12) + hw0 + tx];
    }
    __syncthreads();
#pragma unroll
    for (int r = 0; r < 4; ++r) {
        int row = ty + (r << 3);
        xTb[((size_t)(hw0 + row) << 8) + c0 + tx] = tile[tx][row];
    }
}

// ---------------------------------------------------------------------------
// Kernel 2: pack all weights to bf16, pre-swizzled. Coalesced: one block per
// output row o (or channel ch), contiguous 2304-float read staged in LDS,
// scatter bf16 to the 36 chunks. chunk = k*4 + (c>>6); within-chunk
// pos = (o<<6) + (((ck>>3) ^ (o&7))<<3) + (ck&7), ck = c&63.
// ---------------------------------------------------------------------------
__global__ void prep_weights(const float* __restrict__ w_dcn,
                             const float* __restrict__ w_off,
                             const float* __restrict__ w_mask,
                             unsigned short* __restrict__ wTs,
                             unsigned short* __restrict__ wCs) {
    __shared__ float lw[2304];
    const int t = threadIdx.x;
    if (blockIdx.x < 256) {
        const int o = blockIdx.x;
        for (int e = t; e < 2304; e += 256) lw[e] = w_dcn[(size_t)o * 2304 + e];
        __syncthreads();
        for (int e = t; e < 2304; e += 256) {
            int k = e >> 8, c = e & 255;
            int chunk = (k << 2) + (c >> 6), ck = c & 63;
            int pos = (o << 6) + (((ck >> 3) ^ (o & 7)) << 3) + (ck & 7);
            wTs[(size_t)chunk * 16384 + pos] = f32_to_bf16(lw[c * 9 + k]);
        }
    } else {
        const int ch = blockIdx.x - 256;  // 0..31
        const float* src = (ch < 18) ? w_off + (size_t)ch * 2304
                         : (ch < NCH_) ? w_mask + (size_t)(ch - 18) * 2304
                         : nullptr;
        for (int e = t; e < 2304; e += 256) lw[e] = src ? src[e] : 0.f;
        __syncthreads();
        for (int e = t; e < 2304; e += 256) {
            int k = e >> 8, c = e & 255;
            int chunk = (k << 2) + (c >> 6), ck = c & 63;
            int pos = (ch << 6) + (((ck >> 3) ^ (ch & 7)) << 3) + (ck & 7);
            wCs[(size_t)chunk * 2048 + pos] = f32_to_bf16(lw[c * 9 + k]);
        }
    }
}

// ---------------------------------------------------------------------------
// Kernel 3: offset+mask 3x3 conv via bf16 MFMA, 32 pixels per block.
// grid 512 (2 blocks/CU): b=(bid&7)>>1, ph=bid&1, hh=bid>>3.
// ---------------------------------------------------------------------------
__global__ __launch_bounds__(256, 2) void conv_mfma(
    const float* __restrict__ xT, const unsigned short* __restrict__ wCs,
    const float* __restrict__ b_off, const float* __restrict__ b_mask,
    float* __restrict__ offmask) {
    __shared__ alignas(16) unsigned short wlds[2][2048];   //  8 KB
    __shared__ alignas(16) unsigned short xlds[2][2048];   //  8 KB
    const int t = threadIdx.x;
    const int bid = blockIdx.x;
    const int b = (bid & 7) >> 1;
    const int ph = bid & 1;
    const int hh = bid >> 3;
    const float* xb = xT + ((size_t)b << 20);

    auto stage_w = [&](int chunk, int buf) {
        const unsigned short* g = wCs + ((size_t)chunk << 11) + (t << 3);
        __builtin_amdgcn_global_load_lds(
            (const __attribute__((address_space(1))) unsigned int*)g,
            (__attribute__((address_space(3))) unsigned int*)&wlds[buf][t << 3], 16, 0, 0);
    };

    auto stage_x = [&](int chunk, int buf) {
        int k = chunk >> 2, cc = chunk & 3;
        int ki = k / 3, kj = k % 3;
        int py = hh + ki - 1;
        int p = t >> 3, cs = t & 7;           // 32 p x 8 c-slots = 256
        int px = (ph << 5) + p + kj - 1;
        float4 v0 = make_float4(0.f, 0.f, 0.f, 0.f), v1 = v0;
        if (py >= 0 && py < H_ && px >= 0 && px < W_) {
            const float* src = xb + (((size_t)((py << 6) + px)) << 8) + (cc << 6) + (cs << 3);
            v0 = *(const float4*)src;
            v1 = *(const float4*)(src + 4);
        }
        union { bf16x8 v; unsigned short u[8]; } pk;
        pk.u[0] = f32_to_bf16(v0.x); pk.u[1] = f32_to_bf16(v0.y);
        pk.u[2] = f32_to_bf16(v0.z); pk.u[3] = f32_to_bf16(v0.w);
        pk.u[4] = f32_to_bf16(v1.x); pk.u[5] = f32_to_bf16(v1.y);
        pk.u[6] = f32_to_bf16(v1.z); pk.u[7] = f32_to_bf16(v1.w);
        *(bf16x8*)&xlds[buf][(p << 6) + ((cs ^ (p & 7)) << 3)] = pk.v;
    };

    const int wid = t >> 6, lane = t & 63;
    const int wc = wid >> 1, wp = wid & 1;
    const int m16 = lane & 15, kg = lane >> 4;
    f32x4 acc = {};

    stage_w(0, 0);
    stage_x(0, 0);
    __syncthreads();

    for (int chunk = 0; chunk < 36; ++chunk) {
        int cur = chunk & 1, nxt = cur ^ 1;
        if (chunk < 35) { stage_w(chunk + 1, nxt); stage_x(chunk + 1, nxt); }
#pragma unroll
        for (int ks = 0; ks < 2; ++ks) {
            int s = (ks << 2) + kg;
            int o = (wc << 4) + m16;
            bf16x8 a = *(const bf16x8*)&wlds[cur][(o << 6) + ((s ^ (o & 7)) << 3)];
            int p = (wp << 4) + m16;
            bf16x8 bf = *(const bf16x8*)&xlds[cur][(p << 6) + ((s ^ (p & 7)) << 3)];
            acc = __builtin_amdgcn_mfma_f32_16x16x32_bf16(a, bf, acc, 0, 0, 0);
        }
        __syncthreads();
    }

    const int pix = (hh << 6) + (ph << 5) + (wp << 4) + m16;
#pragma unroll
    for (int r = 0; r < 4; ++r) {
        int ch = (wc << 4) + (kg << 2) + r;
        if (ch < NCH_) {
            float bias = (ch < 18) ? b_off[ch] : b_mask[ch - 18];
            offmask[(((size_t)b * NCH_ + ch) << 12) + pix] = acc[r] + bias;
        }
    }
}

// ---------------------------------------------------------------------------
// Kernel 4: produce the val matrix val[b][chunk=4k+cc][tile32][32p x 64ck bf16,
// pre-swizzled 4KB blocks]. Pure streaming gather+combine+pack: no MFMA, no
// per-chunk barriers; latency hidden by TLP (grid 2304, tiny LDS).
// u32 slot within block: (pl<<5) + (((cpair>>2)^(pl&7))<<2) + (cpair&3).
// ---------------------------------------------------------------------------
__global__ __launch_bounds__(256) void produce_val(
    const float* __restrict__ xT, const float* __restrict__ offmask,
    unsigned int* __restrict__ val) {
    __shared__ float4 cw[64];
    __shared__ ushort4 coff[64];
    const int t = threadIdx.x;
    const int bid = blockIdx.x;
    const int b = bid & 3;
    const int rest = bid >> 2;       // 0..575
    const int k = rest >> 6;         // 0..8
    const int pt = rest & 63;        // 64-pixel group
    const int pix0 = pt << 6;
    const float* xb = xT + ((size_t)b << 20);
    const float* omb = offmask + (((size_t)b * NCH_) << 12);

    if (t < 64) {
        int p = t;
        int pix = pix0 + p;
        int hh = pix >> 6, ww = pix & 63;
        float dy = omb[((size_t)(2 * k) << 12) + pix];
        float dx = omb[((size_t)(2 * k + 1) << 12) + pix];
        float ml = omb[((size_t)(18 + k) << 12) + pix];
        float m = 1.f / (1.f + __expf(-ml));
        float py = (float)(hh - 1 + (k / 3)) + dy;
        float px = (float)(ww - 1 + (k % 3)) + dx;
        float fy0 = floorf(py), fx0 = floorf(px);
        float ay = py - fy0, ax = px - fx0;
        bool y0v = (fy0 >= 0.f) && (fy0 <= 63.f);
        bool y1v = (fy0 >= -1.f) && (fy0 <= 62.f);
        bool x0v = (fx0 >= 0.f) && (fx0 <= 63.f);
        bool x1v = (fx0 >= -1.f) && (fx0 <= 62.f);
        int y0 = (int)fy0, x0 = (int)fx0;
        int iy0 = min(max(y0, 0), 63), iy1 = min(max(y0 + 1, 0), 63);
        int ix0 = min(max(x0, 0), 63), ix1 = min(max(x0 + 1, 0), 63);
        float w00 = (y0v && x0v) ? m * (1.f - ay) * (1.f - ax) : 0.f;
        float w01 = (y0v && x1v) ? m * (1.f - ay) * ax : 0.f;
        float w10 = (y1v && x0v) ? m * ay * (1.f - ax) : 0.f;
        float w11 = (y1v && x1v) ? m * ay * ax : 0.f;
        cw[p] = make_float4(w00, w01, w10, w11);
        coff[p] = make_ushort4((unsigned short)((iy0 << 6) + ix0),
                               (unsigned short)((iy0 << 6) + ix1),
                               (unsigned short)((iy1 << 6) + ix0),
                               (unsigned short)((iy1 << 6) + ix1));
    }
    __syncthreads();

    const int cq = t & 15, pg = t >> 4;      // cquad (4 channels) x 16 p-groups
#pragma unroll
    for (int cc = 0; cc < 4; ++cc) {
        const size_t blockbase = ((size_t)((b * 36 + (k << 2) + cc)) << 7) + (pt << 1);
        const float* cbase = xb + (cc << 6) + (cq << 2);
#pragma unroll
        for (int i = 0; i < 4; ++i) {
            int p = (pg << 2) + i;
            ushort4 o4 = coff[p];
            float4 w4 = cw[p];
            float4 s0 = *(const float4*)(cbase + ((int)o4.x << 8));
            float4 s1 = *(const float4*)(cbase + ((int)o4.y << 8));
            float4 s2 = *(const float4*)(cbase + ((int)o4.z << 8));
            float4 s3 = *(const float4*)(cbase + ((int)o4.w << 8));
            float v0 = w4.x * s0.x + w4.y * s1.x + w4.z * s2.x + w4.w * s3.x;
            float v1 = w4.x * s0.y + w4.y * s1.y + w4.z * s2.y + w4.w * s3.y;
            float v2 = w4.x * s0.z + w4.y * s1.z + w4.z * s2.z + w4.w * s3.z;
            float v3 = w4.x * s0.w + w4.y * s1.w + w4.z * s2.w + w4.w * s3.w;
            uint2 pk;
            pk.x = (unsigned int)f32_to_bf16(v0) | ((unsigned int)f32_to_bf16(v1) << 16);
            pk.y = (unsigned int)f32_to_bf16(v2) | ((unsigned int)f32_to_bf16(v3) << 16);
            int pl = p & 31;
            size_t idx = ((blockbase + (p >> 5)) << 10) + (pl << 5)
                       + (((cq >> 1) ^ (pl & 7)) << 2) + ((cq & 1) << 1);
            *(uint2*)(val + idx) = pk;
        }
    }
}

// ---------------------------------------------------------------------------
// Kernel 5: pure bf16 MFMA GEMM: out[b][256o][32p tile] += wTs . val.
// grid 512 (2 blocks/CU): b=(bid&7)>>1, tile=(bid>>3)+((bid&1)<<6).
// 512 thr = 8 waves (4 o-rows x 2 p-cols), wave = 64o x 16p, acc[4] f32x4.
// Per chunk: stage_w (32 KB) + stage_v (4 KB) DMA, 8 MFMA/wave, 1 barrier.
// LDS: 65536 + 8192 = 73728 B -> 2 blocks/CU.
// ---------------------------------------------------------------------------
__global__ __launch_bounds__(512, 4) void dcn_gemm(
    const unsigned short* __restrict__ val, const unsigned short* __restrict__ wTs,
    const float* __restrict__ b_dcn, float* __restrict__ out) {
    __shared__ alignas(16) unsigned short wbuf[2][16384];   // 65536 B
    __shared__ alignas(16) unsigned short vbuf[2][2048];    //  8192 B

    const int t = threadIdx.x;
    const int bid = blockIdx.x;
    const int b = (bid & 7) >> 1;
    const int tile = (bid >> 3) + ((bid & 1) << 6);   // 0..127
    const int pix0 = tile << 5;

    const int wid = t >> 6, lane = t & 63;
    const int wo = wid >> 1, wp = wid & 1;
    const int m16 = lane & 15, kg = lane >> 4;

    auto stage_w = [&](int chunk, int buf) {
#pragma unroll
        for (int r = 0; r < 4; ++r) {
            int off16 = (r << 9) + t;   // 16B units, 0..2047
            const unsigned short* g = wTs + ((size_t)chunk << 14) + (off16 << 3);
            unsigned short* l = &wbuf[buf][off16 << 3];
            __builtin_amdgcn_global_load_lds(
                (const __attribute__((address_space(1))) unsigned int*)g,
                (__attribute__((address_space(3))) unsigned int*)l, 16, 0, 0);
        }
    };

    auto stage_v = [&](int chunk, int buf) {
        if (t < 256) {
            const unsigned short* g = val + ((((size_t)(b * 36 + chunk)) << 7) + tile) * 2048 + (t << 3);
            __builtin_amdgcn_global_load_lds(
                (const __attribute__((address_space(1))) unsigned int*)g,
                (__attribute__((address_space(3))) unsigned int*)&vbuf[buf][t << 3], 16, 0, 0);
        }
    };

    f32x4 acc[4] = {};

    stage_w(0, 0);
    stage_v(0, 0);
    __syncthreads();

    for (int chunk = 0; chunk < 36; ++chunk) {
        int cur = chunk & 1, nxt = cur ^ 1;
        if (chunk < 35) {
            stage_w(chunk + 1, nxt);
            stage_v(chunk + 1, nxt);
        }
#pragma unroll
        for (int ks = 0; ks < 2; ++ks) {
            int s = (ks << 2) + kg;
            bf16x8 aF[4], bF;
#pragma unroll
            for (int i = 0; i < 4; ++i) {
                int o = (wo << 6) + (i << 4) + m16;
                aF[i] = *(const bf16x8*)&wbuf[cur][(o << 6) + ((s ^ (o & 7)) << 3)];
            }
            {
                int p = (wp << 4) + m16;
                bF = *(const bf16x8*)&vbuf[cur][(p << 6) + ((s ^ (p & 7)) << 3)];
            }
#pragma unroll
            for (int i = 0; i < 4; ++i)
                acc[i] = __builtin_amdgcn_mfma_f32_16x16x32_bf16(aF[i], bF, acc[i], 0, 0, 0);
        }
        __syncthreads();
    }

    // epilogue: C/D layout col=lane&15 (pixel), row=(lane>>4)*4+r (o within 16)
#pragma unroll
    for (int i = 0; i < 4; ++i) {
        int ob = (wo << 6) + (i << 4) + (kg << 2);
        int p = pix0 + (wp << 4) + m16;
#pragma unroll
        for (int r = 0; r < 4; ++r) {
            int oo = ob + r;
            out[(((size_t)(b << 8) + oo) << 12) + p] = acc[i][r] + b_dcn[oo];
        }
    }
}

// ---------------------------------------------------------------------------
extern "C" void kernel_launch(void* const* d_in, const int* in_sizes, int n_in,
                              void* d_out, int out_size, void* d_ws, size_t ws_size,
                              hipStream_t stream) {
    const float* x      = (const float*)d_in[0];
    const float* w_off  = (const float*)d_in[1];
    const float* b_off  = (const float*)d_in[2];
    const float* w_mask = (const float*)d_in[3];
    const float* b_mask = (const float*)d_in[4];
    const float* w_dcn  = (const float*)d_in[5];
    const float* b_dcn  = (const float*)d_in[6];
    float* out = (float*)d_out;

    float* ws = (float*)d_ws;
    float* xT      = ws;                                  //  16.78 MB
    float* offmask = xT + (size_t)B_ * HW_ * C_;          //   1.77 MB
    unsigned short* wTs = (unsigned short*)(offmask + (size_t)B_ * NCH_ * HW_); // 1.18 MB
    unsigned short* wCs = wTs + (size_t)36 * 16384;       //   0.15 MB
    unsigned int* val   = (unsigned int*)(wCs + (size_t)36 * 2048); // 73.7 MB
    // total ~93.6 MB of d_ws

    transpose_x<<<dim3(4096), dim3(256), 0, stream>>>(x, xT);
    prep_weights<<<dim3(288), dim3(256), 0, stream>>>(w_dcn, w_off, w_mask, wTs, wCs);
    conv_mfma<<<dim3(512), dim3(256), 0, stream>>>(xT, wCs, b_off, b_mask, offmask);
    produce_val<<<dim3(2304), dim3(256), 0, stream>>>(xT, offmask, val);
    dcn_gemm<<<dim3(512), dim3(512), 0, stream>>>((const unsigned short*)val, wTs, b_dcn, out);
}

// Round 8
// 90.622 us; speedup vs baseline: 4.2915x; 1.1657x over previous
//
#include <hip/hip_runtime.h>
#include <math.h>

// Problem constants
#define B_ 4
#define C_ 256
#define CO_ 256
#define H_ 64
#define W_ 64
#define HW_ 4096
#define KK_ 9   // 3x3 kernel positions
#define NCH_ 27 // 18 offset + 9 mask channels

typedef __attribute__((ext_vector_type(8))) short bf16x8;
typedef __attribute__((ext_vector_type(4))) float f32x4;

__device__ inline unsigned short f32_to_bf16(float f) {
    unsigned int u = __float_as_uint(f);
    unsigned int r = (u + 0x7FFFu + ((u >> 16) & 1u)) >> 16;  // RNE
    return (unsigned short)r;
}

// ---------------------------------------------------------------------------
// Kernel 1: transpose x NCHW f32 -> NHWC bf16 (xTh[b][hw][c])
// ---------------------------------------------------------------------------
__global__ void transpose_x(const float* __restrict__ x, unsigned short* __restrict__ xTh) {
    __shared__ float tile[32][33];
    const int t = threadIdx.x;
    const int tx = t & 31, ty = t >> 5;
    const int b = blockIdx.x >> 10;
    const int rem = blockIdx.x & 1023;
    const int c0 = (rem >> 7) << 5;
    const int hw0 = (rem & 127) << 5;
    const float* xb = x + ((size_t)b << 20);
    unsigned short* xTb = xTh + ((size_t)b << 20);
#pragma unroll
    for (int r = 0; r < 4; ++r) {
        int row = ty + (r << 3);
        tile[row][tx] = xb[((size_t)(c0 + row) << 12) + hw0 + tx];
    }
    __syncthreads();
#pragma unroll
    for (int r = 0; r < 4; ++r) {
        int row = ty + (r << 3);
        xTb[((size_t)(hw0 + row) << 8) + c0 + tx] = f32_to_bf16(tile[tx][row]);
    }
}

// ---------------------------------------------------------------------------
// Kernel 2: pack all weights to bf16, pre-swizzled. chunk = k*4 + (c>>6);
// within-chunk pos = (o<<6) + (((ck>>3) ^ (o&7))<<3) + (ck&7), ck = c&63.
// ---------------------------------------------------------------------------
__global__ void prep_weights(const float* __restrict__ w_dcn,
                             const float* __restrict__ w_off,
                             const float* __restrict__ w_mask,
                             unsigned short* __restrict__ wTs,
                             unsigned short* __restrict__ wCs) {
    __shared__ float lw[2304];
    const int t = threadIdx.x;
    if (blockIdx.x < 256) {
        const int o = blockIdx.x;
        for (int e = t; e < 2304; e += 256) lw[e] = w_dcn[(size_t)o * 2304 + e];
        __syncthreads();
        for (int e = t; e < 2304; e += 256) {
            int k = e >> 8, c = e & 255;
            int chunk = (k << 2) + (c >> 6), ck = c & 63;
            int pos = (o << 6) + (((ck >> 3) ^ (o & 7)) << 3) + (ck & 7);
            wTs[(size_t)chunk * 16384 + pos] = f32_to_bf16(lw[c * 9 + k]);
        }
    } else {
        const int ch = blockIdx.x - 256;  // 0..31
        const float* src = (ch < 18) ? w_off + (size_t)ch * 2304
                         : (ch < NCH_) ? w_mask + (size_t)(ch - 18) * 2304
                         : nullptr;
        for (int e = t; e < 2304; e += 256) lw[e] = src ? src[e] : 0.f;
        __syncthreads();
        for (int e = t; e < 2304; e += 256) {
            int k = e >> 8, c = e & 255;
            int chunk = (k << 2) + (c >> 6), ck = c & 63;
            int pos = (ch << 6) + (((ck >> 3) ^ (ch & 7)) << 3) + (ck & 7);
            wCs[(size_t)chunk * 2048 + pos] = f32_to_bf16(lw[c * 9 + k]);
        }
    }
}

// ---------------------------------------------------------------------------
// Kernel 3: offset+mask 3x3 conv via bf16 MFMA, 32 pixels per block.
// grid 512 (2 blocks/CU): b=(bid&7)>>1, ph=bid&1, hh=bid>>3.
// stage_x reads bf16 xTh directly -> zero conversion cost.
// ---------------------------------------------------------------------------
__global__ __launch_bounds__(256, 2) void conv_mfma(
    const unsigned short* __restrict__ xTh, const unsigned short* __restrict__ wCs,
    const float* __restrict__ b_off, const float* __restrict__ b_mask,
    float* __restrict__ offmask) {
    __shared__ alignas(16) unsigned short wlds[2][2048];   //  8 KB
    __shared__ alignas(16) unsigned short xlds[2][2048];   //  8 KB
    const int t = threadIdx.x;
    const int bid = blockIdx.x;
    const int b = (bid & 7) >> 1;
    const int ph = bid & 1;
    const int hh = bid >> 3;
    const unsigned short* xb = xTh + ((size_t)b << 20);

    auto stage_w = [&](int chunk, int buf) {
        const unsigned short* g = wCs + ((size_t)chunk << 11) + (t << 3);
        __builtin_amdgcn_global_load_lds(
            (const __attribute__((address_space(1))) unsigned int*)g,
            (__attribute__((address_space(3))) unsigned int*)&wlds[buf][t << 3], 16, 0, 0);
    };

    auto stage_x = [&](int chunk, int buf) {
        int k = chunk >> 2, cc = chunk & 3;
        int ki = k / 3, kj = k % 3;
        int py = hh + ki - 1;
        int p = t >> 3, cs = t & 7;           // 32 p x 8 c-octs = 256
        int px = (ph << 5) + p + kj - 1;
        uint4 u = make_uint4(0u, 0u, 0u, 0u);
        if (py >= 0 && py < H_ && px >= 0 && px < W_)
            u = *(const uint4*)(xb + (((size_t)((py << 6) + px)) << 8) + (cc << 6) + (cs << 3));
        *(uint4*)&xlds[buf][(p << 6) + ((cs ^ (p & 7)) << 3)] = u;
    };

    const int wid = t >> 6, lane = t & 63;
    const int wc = wid >> 1, wp = wid & 1;
    const int m16 = lane & 15, kg = lane >> 4;
    f32x4 acc = {};

    stage_w(0, 0);
    stage_x(0, 0);
    __syncthreads();

    for (int chunk = 0; chunk < 36; ++chunk) {
        int cur = chunk & 1, nxt = cur ^ 1;
        if (chunk < 35) { stage_w(chunk + 1, nxt); stage_x(chunk + 1, nxt); }
#pragma unroll
        for (int ks = 0; ks < 2; ++ks) {
            int s = (ks << 2) + kg;
            int o = (wc << 4) + m16;
            bf16x8 a = *(const bf16x8*)&wlds[cur][(o << 6) + ((s ^ (o & 7)) << 3)];
            int p = (wp << 4) + m16;
            bf16x8 bf = *(const bf16x8*)&xlds[cur][(p << 6) + ((s ^ (p & 7)) << 3)];
            acc = __builtin_amdgcn_mfma_f32_16x16x32_bf16(a, bf, acc, 0, 0, 0);
        }
        __syncthreads();
    }

    const int pix = (hh << 6) + (ph << 5) + (wp << 4) + m16;
#pragma unroll
    for (int r = 0; r < 4; ++r) {
        int ch = (wc << 4) + (kg << 2) + r;
        if (ch < NCH_) {
            float bias = (ch < 18) ? b_off[ch] : b_mask[ch - 18];
            offmask[(((size_t)b * NCH_ + ch) << 12) + pix] = acc[r] + bias;
        }
    }
}

// ---------------------------------------------------------------------------
// Kernel 4: produce val[b][chunk][tile32][32p x 64ck bf16, swizzled 4KB blocks]
// from bf16 xTh. Thread = (8ch-oct x 32p); 2 p-passes x 4 cc chunks.
// Gathers are 16B/corner, 128B coalesced across octs. No barriers in loop.
// ---------------------------------------------------------------------------
__global__ __launch_bounds__(256) void produce_val(
    const unsigned short* __restrict__ xTh, const float* __restrict__ offmask,
    unsigned short* __restrict__ val) {
    __shared__ float4 cw[64];
    __shared__ ushort4 coff[64];
    const int t = threadIdx.x;
    const int bid = blockIdx.x;
    const int b = bid & 3;
    const int rest = bid >> 2;       // 0..575
    const int k = rest >> 6;         // 0..8
    const int pt = rest & 63;        // 64-pixel group
    const int pix0 = pt << 6;
    const unsigned short* xb = xTh + ((size_t)b << 20);
    const float* omb = offmask + (((size_t)b * NCH_) << 12);

    if (t < 64) {
        int p = t;
        int pix = pix0 + p;
        int hh = pix >> 6, ww = pix & 63;
        float dy = omb[((size_t)(2 * k) << 12) + pix];
        float dx = omb[((size_t)(2 * k + 1) << 12) + pix];
        float ml = omb[((size_t)(18 + k) << 12) + pix];
        float m = 1.f / (1.f + __expf(-ml));
        float py = (float)(hh - 1 + (k / 3)) + dy;
        float px = (float)(ww - 1 + (k % 3)) + dx;
        float fy0 = floorf(py), fx0 = floorf(px);
        float ay = py - fy0, ax = px - fx0;
        bool y0v = (fy0 >= 0.f) && (fy0 <= 63.f);
        bool y1v = (fy0 >= -1.f) && (fy0 <= 62.f);
        bool x0v = (fx0 >= 0.f) && (fx0 <= 63.f);
        bool x1v = (fx0 >= -1.f) && (fx0 <= 62.f);
        int y0 = (int)fy0, x0 = (int)fx0;
        int iy0 = min(max(y0, 0), 63), iy1 = min(max(y0 + 1, 0), 63);
        int ix0 = min(max(x0, 0), 63), ix1 = min(max(x0 + 1, 0), 63);
        float w00 = (y0v && x0v) ? m * (1.f - ay) * (1.f - ax) : 0.f;
        float w01 = (y0v && x1v) ? m * (1.f - ay) * ax : 0.f;
        float w10 = (y1v && x0v) ? m * ay * (1.f - ax) : 0.f;
        float w11 = (y1v && x1v) ? m * ay * ax : 0.f;
        cw[p] = make_float4(w00, w01, w10, w11);
        coff[p] = make_ushort4((unsigned short)((iy0 << 6) + ix0),
                               (unsigned short)((iy0 << 6) + ix1),
                               (unsigned short)((iy1 << 6) + ix0),
                               (unsigned short)((iy1 << 6) + ix1));
    }
    __syncthreads();

    const int oct = t & 7, pq = t >> 3;      // 8 c-octs x 32 pixels
#pragma unroll
    for (int pp = 0; pp < 2; ++pp) {
        int p = (pp << 5) + pq;              // 0..63
        ushort4 o4 = coff[p];
        float4 w4 = cw[p];
        const int slot = (pq << 6) + ((oct ^ (pq & 7)) << 3);
#pragma unroll
        for (int cc = 0; cc < 4; ++cc) {
            int cb = (cc << 6) + (oct << 3);
            union { uint4 v; unsigned int u[4]; } A, B2, C2, D2;
            A.v  = *(const uint4*)(xb + ((int)o4.x << 8) + cb);
            B2.v = *(const uint4*)(xb + ((int)o4.y << 8) + cb);
            C2.v = *(const uint4*)(xb + ((int)o4.z << 8) + cb);
            D2.v = *(const uint4*)(xb + ((int)o4.w << 8) + cb);
            unsigned short o8[8];
#pragma unroll
            for (int j = 0; j < 4; ++j) {
                float al = __uint_as_float(A.u[j] << 16);
                float ah = __uint_as_float(A.u[j] & 0xffff0000u);
                float bl = __uint_as_float(B2.u[j] << 16);
                float bh = __uint_as_float(B2.u[j] & 0xffff0000u);
                float cl = __uint_as_float(C2.u[j] << 16);
                float ch = __uint_as_float(C2.u[j] & 0xffff0000u);
                float dl = __uint_as_float(D2.u[j] << 16);
                float dh = __uint_as_float(D2.u[j] & 0xffff0000u);
                float vl = w4.x * al + w4.y * bl + w4.z * cl + w4.w * dl;
                float vh = w4.x * ah + w4.y * bh + w4.z * ch + w4.w * dh;
                o8[2 * j]     = f32_to_bf16(vl);
                o8[2 * j + 1] = f32_to_bf16(vh);
            }
            size_t base = ((size_t)(b * 36 + (k << 2) + cc) * 128 + (pt << 1) + pp) * 2048;
            *(uint4*)(val + base + slot) = *(const uint4*)o8;
        }
    }
}

// ---------------------------------------------------------------------------
// Kernel 5: pure bf16 MFMA GEMM, 64 pixels/block: out[b][256o][64p] = wTs.val.
// grid 256 (1 block/CU): b=(bid&7)>>1, tile64=(bid>>3)+((bid&1)<<5).
// 512 thr = 8 waves (4 o-rows x 2 p-cols), wave = 64o x 32p, acc[4][2].
// Per chunk: stage_w 32KB + stage_v 8KB linear DMA, 16 MFMA/wave, 1 barrier.
// LDS: 65536 + 16384 = 80 KB.
// ---------------------------------------------------------------------------
__global__ __launch_bounds__(512, 2) void dcn_gemm(
    const unsigned short* __restrict__ val, const unsigned short* __restrict__ wTs,
    const float* __restrict__ b_dcn, float* __restrict__ out) {
    __shared__ alignas(16) unsigned short wbuf[2][16384];   // 65536 B
    __shared__ alignas(16) unsigned short vbuf[2][4096];    // 16384 B

    const int t = threadIdx.x;
    const int bid = blockIdx.x;
    const int b = (bid & 7) >> 1;
    const int tile64 = (bid >> 3) + ((bid & 1) << 5);   // 0..63
    const int pix0 = tile64 << 6;

    const int wid = t >> 6, lane = t & 63;
    const int wo = wid >> 1, wp = wid & 1;
    const int m16 = lane & 15, kg = lane >> 4;

    auto stage_w = [&](int chunk, int buf) {
#pragma unroll
        for (int r = 0; r < 4; ++r) {
            int off16 = (r << 9) + t;   // 16B units, 0..2047
            const unsigned short* g = wTs + ((size_t)chunk << 14) + (off16 << 3);
            unsigned short* l = &wbuf[buf][off16 << 3];
            __builtin_amdgcn_global_load_lds(
                (const __attribute__((address_space(1))) unsigned int*)g,
                (__attribute__((address_space(3))) unsigned int*)l, 16, 0, 0);
        }
    };

    auto stage_v = [&](int chunk, int buf) {
        // two consecutive 4KB val tiles = one linear 8KB copy
        const unsigned short* g = val + ((size_t)(b * 36 + chunk) * 128 + (tile64 << 1)) * 2048 + (t << 3);
        __builtin_amdgcn_global_load_lds(
            (const __attribute__((address_space(1))) unsigned int*)g,
            (__attribute__((address_space(3))) unsigned int*)&vbuf[buf][t << 3], 16, 0, 0);
    };

    f32x4 acc[4][2] = {};

    stage_w(0, 0);
    stage_v(0, 0);
    __syncthreads();

    for (int chunk = 0; chunk < 36; ++chunk) {
        int cur = chunk & 1, nxt = cur ^ 1;
        if (chunk < 35) {
            stage_w(chunk + 1, nxt);
            stage_v(chunk + 1, nxt);
        }
#pragma unroll
        for (int ks = 0; ks < 2; ++ks) {
            int s = (ks << 2) + kg;
            bf16x8 aF[4], bF[2];
#pragma unroll
            for (int i = 0; i < 4; ++i) {
                int o = (wo << 6) + (i << 4) + m16;
                aF[i] = *(const bf16x8*)&wbuf[cur][(o << 6) + ((s ^ (o & 7)) << 3)];
            }
#pragma unroll
            for (int j = 0; j < 2; ++j) {
                int p = (wp << 5) + (j << 4) + m16;   // 0..63
                int th = p >> 5, p32 = p & 31;
                bF[j] = *(const bf16x8*)&vbuf[cur][(th << 11) + (p32 << 6) + ((s ^ (p32 & 7)) << 3)];
            }
#pragma unroll
            for (int i = 0; i < 4; ++i)
#pragma unroll
                for (int j = 0; j < 2; ++j)
                    acc[i][j] = __builtin_amdgcn_mfma_f32_16x16x32_bf16(
                        aF[i], bF[j], acc[i][j], 0, 0, 0);
        }
        __syncthreads();
    }

    // epilogue: C/D layout col=lane&15 (pixel), row=(lane>>4)*4+r (o within 16)
#pragma unroll
    for (int i = 0; i < 4; ++i) {
        int ob = (wo << 6) + (i << 4) + (kg << 2);
#pragma unroll
        for (int j = 0; j < 2; ++j) {
            int p = pix0 + (wp << 5) + (j << 4) + m16;
#pragma unroll
            for (int r = 0; r < 4; ++r) {
                int oo = ob + r;
                out[(((size_t)(b << 8) + oo) << 12) + p] = acc[i][j][r] + b_dcn[oo];
            }
        }
    }
}

// ---------------------------------------------------------------------------
extern "C" void kernel_launch(void* const* d_in, const int* in_sizes, int n_in,
                              void* d_out, int out_size, void* d_ws, size_t ws_size,
                              hipStream_t stream) {
    const float* x      = (const float*)d_in[0];
    const float* w_off  = (const float*)d_in[1];
    const float* b_off  = (const float*)d_in[2];
    const float* w_mask = (const float*)d_in[3];
    const float* b_mask = (const float*)d_in[4];
    const float* w_dcn  = (const float*)d_in[5];
    const float* b_dcn  = (const float*)d_in[6];
    float* out = (float*)d_out;

    float* ws = (float*)d_ws;
    float* offmask = ws;                                       //  1.77 MB
    unsigned short* xTh = (unsigned short*)(offmask + (size_t)B_ * NCH_ * HW_); // 8.39 MB
    unsigned short* wTs = xTh + ((size_t)B_ * HW_ * C_);       //  1.18 MB
    unsigned short* wCs = wTs + (size_t)36 * 16384;            //  0.15 MB
    unsigned short* val = wCs + (size_t)36 * 2048;             // 75.5 MB
    // total ~87 MB of d_ws

    transpose_x<<<dim3(4096), dim3(256), 0, stream>>>(x, xTh);
    prep_weights<<<dim3(288), dim3(256), 0, stream>>>(w_dcn, w_off, w_mask, wTs, wCs);
    conv_mfma<<<dim3(512), dim3(256), 0, stream>>>(xTh, wCs, b_off, b_mask, offmask);
    produce_val<<<dim3(2304), dim3(256), 0, stream>>>(xTh, offmask, val);
    dcn_gemm<<<dim3(256), dim3(512), 0, stream>>>(val, wTs, b_dcn, out);
}

// Round 9
// 87.441 us; speedup vs baseline: 4.4476x; 1.0364x over previous
//
#include <hip/hip_runtime.h>
#include <math.h>

// Problem constants
#define B_ 4
#define C_ 256
#define CO_ 256
#define H_ 64
#define W_ 64
#define HW_ 4096
#define KK_ 9   // 3x3 kernel positions
#define NCH_ 27 // 18 offset + 9 mask channels

typedef __attribute__((ext_vector_type(8))) short bf16x8;
typedef __attribute__((ext_vector_type(4))) float f32x4;

__device__ inline unsigned short f32_to_bf16(float f) {
    unsigned int u = __float_as_uint(f);
    unsigned int r = (u + 0x7FFFu + ((u >> 16) & 1u)) >> 16;  // RNE
    return (unsigned short)r;
}

// ---------------------------------------------------------------------------
// Kernel 1: transpose x NCHW f32 -> NHWC bf16 (xTh[b][hw][c])
// ---------------------------------------------------------------------------
__global__ void transpose_x(const float* __restrict__ x, unsigned short* __restrict__ xTh) {
    __shared__ float tile[32][33];
    const int t = threadIdx.x;
    const int tx = t & 31, ty = t >> 5;
    const int b = blockIdx.x >> 10;
    const int rem = blockIdx.x & 1023;
    const int c0 = (rem >> 7) << 5;
    const int hw0 = (rem & 127) << 5;
    const float* xb = x + ((size_t)b << 20);
    unsigned short* xTb = xTh + ((size_t)b << 20);
#pragma unroll
    for (int r = 0; r < 4; ++r) {
        int row = ty + (r << 3);
        tile[row][tx] = xb[((size_t)(c0 + row) << 12) + hw0 + tx];
    }
    __syncthreads();
#pragma unroll
    for (int r = 0; r < 4; ++r) {
        int row = ty + (r << 3);
        xTb[((size_t)(hw0 + row) << 8) + c0 + tx] = f32_to_bf16(tile[tx][row]);
    }
}

// ---------------------------------------------------------------------------
// Kernel 2: pack all weights to bf16, pre-swizzled. chunk = k*4 + (c>>6);
// within-chunk pos = (o<<6) + (((ck>>3) ^ (o&7))<<3) + (ck&7), ck = c&63.
// ---------------------------------------------------------------------------
__global__ void prep_weights(const float* __restrict__ w_dcn,
                             const float* __restrict__ w_off,
                             const float* __restrict__ w_mask,
                             unsigned short* __restrict__ wTs,
                             unsigned short* __restrict__ wCs) {
    __shared__ float lw[2304];
    const int t = threadIdx.x;
    if (blockIdx.x < 256) {
        const int o = blockIdx.x;
        for (int e = t; e < 2304; e += 256) lw[e] = w_dcn[(size_t)o * 2304 + e];
        __syncthreads();
        for (int e = t; e < 2304; e += 256) {
            int k = e >> 8, c = e & 255;
            int chunk = (k << 2) + (c >> 6), ck = c & 63;
            int pos = (o << 6) + (((ck >> 3) ^ (o & 7)) << 3) + (ck & 7);
            wTs[(size_t)chunk * 16384 + pos] = f32_to_bf16(lw[c * 9 + k]);
        }
    } else {
        const int ch = blockIdx.x - 256;  // 0..31
        const float* src = (ch < 18) ? w_off + (size_t)ch * 2304
                         : (ch < NCH_) ? w_mask + (size_t)(ch - 18) * 2304
                         : nullptr;
        for (int e = t; e < 2304; e += 256) lw[e] = src ? src[e] : 0.f;
        __syncthreads();
        for (int e = t; e < 2304; e += 256) {
            int k = e >> 8, c = e & 255;
            int chunk = (k << 2) + (c >> 6), ck = c & 63;
            int pos = (ch << 6) + (((ck >> 3) ^ (ch & 7)) << 3) + (ck & 7);
            wCs[(size_t)chunk * 2048 + pos] = f32_to_bf16(lw[c * 9 + k]);
        }
    }
}

// ---------------------------------------------------------------------------
// Kernel 3: offset+mask 3x3 conv via bf16 MFMA, 32 pixels per block.
// grid 512 (2 blocks/CU): b=(bid&7)>>1, ph=bid&1, hh=bid>>3.
// ---------------------------------------------------------------------------
__global__ __launch_bounds__(256, 2) void conv_mfma(
    const unsigned short* __restrict__ xTh, const unsigned short* __restrict__ wCs,
    const float* __restrict__ b_off, const float* __restrict__ b_mask,
    float* __restrict__ offmask) {
    __shared__ alignas(16) unsigned short wlds[2][2048];   //  8 KB
    __shared__ alignas(16) unsigned short xlds[2][2048];   //  8 KB
    const int t = threadIdx.x;
    const int bid = blockIdx.x;
    const int b = (bid & 7) >> 1;
    const int ph = bid & 1;
    const int hh = bid >> 3;
    const unsigned short* xb = xTh + ((size_t)b << 20);

    auto stage_w = [&](int chunk, int buf) {
        const unsigned short* g = wCs + ((size_t)chunk << 11) + (t << 3);
        __builtin_amdgcn_global_load_lds(
            (const __attribute__((address_space(1))) unsigned int*)g,
            (__attribute__((address_space(3))) unsigned int*)&wlds[buf][t << 3], 16, 0, 0);
    };

    auto stage_x = [&](int chunk, int buf) {
        int k = chunk >> 2, cc = chunk & 3;
        int ki = k / 3, kj = k % 3;
        int py = hh + ki - 1;
        int p = t >> 3, cs = t & 7;           // 32 p x 8 c-octs = 256
        int px = (ph << 5) + p + kj - 1;
        uint4 u = make_uint4(0u, 0u, 0u, 0u);
        if (py >= 0 && py < H_ && px >= 0 && px < W_)
            u = *(const uint4*)(xb + (((size_t)((py << 6) + px)) << 8) + (cc << 6) + (cs << 3));
        *(uint4*)&xlds[buf][(p << 6) + ((cs ^ (p & 7)) << 3)] = u;
    };

    const int wid = t >> 6, lane = t & 63;
    const int wc = wid >> 1, wp = wid & 1;
    const int m16 = lane & 15, kg = lane >> 4;
    f32x4 acc = {};

    stage_w(0, 0);
    stage_x(0, 0);
    __syncthreads();

    for (int chunk = 0; chunk < 36; ++chunk) {
        int cur = chunk & 1, nxt = cur ^ 1;
        if (chunk < 35) { stage_w(chunk + 1, nxt); stage_x(chunk + 1, nxt); }
#pragma unroll
        for (int ks = 0; ks < 2; ++ks) {
            int s = (ks << 2) + kg;
            int o = (wc << 4) + m16;
            bf16x8 a = *(const bf16x8*)&wlds[cur][(o << 6) + ((s ^ (o & 7)) << 3)];
            int p = (wp << 4) + m16;
            bf16x8 bf = *(const bf16x8*)&xlds[cur][(p << 6) + ((s ^ (p & 7)) << 3)];
            acc = __builtin_amdgcn_mfma_f32_16x16x32_bf16(a, bf, acc, 0, 0, 0);
        }
        __syncthreads();
    }

    const int pix = (hh << 6) + (ph << 5) + (wp << 4) + m16;
#pragma unroll
    for (int r = 0; r < 4; ++r) {
        int ch = (wc << 4) + (kg << 2) + r;
        if (ch < NCH_) {
            float bias = (ch < 18) ? b_off[ch] : b_mask[ch - 18];
            offmask[(((size_t)b * NCH_ + ch) << 12) + pix] = acc[r] + bias;
        }
    }
}

// ---------------------------------------------------------------------------
// Kernel 4: produce val[b][chunk][tile32][32p x 64ck bf16, swizzled 4KB blocks]
// from bf16 xTh. Thread = (8ch-oct x 32p); 2 p-passes x 4 cc chunks.
// ---------------------------------------------------------------------------
__global__ __launch_bounds__(256) void produce_val(
    const unsigned short* __restrict__ xTh, const float* __restrict__ offmask,
    unsigned short* __restrict__ val) {
    __shared__ float4 cw[64];
    __shared__ ushort4 coff[64];
    const int t = threadIdx.x;
    const int bid = blockIdx.x;
    const int b = bid & 3;
    const int rest = bid >> 2;       // 0..575
    const int k = rest >> 6;         // 0..8
    const int pt = rest & 63;        // 64-pixel group
    const int pix0 = pt << 6;
    const unsigned short* xb = xTh + ((size_t)b << 20);
    const float* omb = offmask + (((size_t)b * NCH_) << 12);

    if (t < 64) {
        int p = t;
        int pix = pix0 + p;
        int hh = pix >> 6, ww = pix & 63;
        float dy = omb[((size_t)(2 * k) << 12) + pix];
        float dx = omb[((size_t)(2 * k + 1) << 12) + pix];
        float ml = omb[((size_t)(18 + k) << 12) + pix];
        float m = 1.f / (1.f + __expf(-ml));
        float py = (float)(hh - 1 + (k / 3)) + dy;
        float px = (float)(ww - 1 + (k % 3)) + dx;
        float fy0 = floorf(py), fx0 = floorf(px);
        float ay = py - fy0, ax = px - fx0;
        bool y0v = (fy0 >= 0.f) && (fy0 <= 63.f);
        bool y1v = (fy0 >= -1.f) && (fy0 <= 62.f);
        bool x0v = (fx0 >= 0.f) && (fx0 <= 63.f);
        bool x1v = (fx0 >= -1.f) && (fx0 <= 62.f);
        int y0 = (int)fy0, x0 = (int)fx0;
        int iy0 = min(max(y0, 0), 63), iy1 = min(max(y0 + 1, 0), 63);
        int ix0 = min(max(x0, 0), 63), ix1 = min(max(x0 + 1, 0), 63);
        float w00 = (y0v && x0v) ? m * (1.f - ay) * (1.f - ax) : 0.f;
        float w01 = (y0v && x1v) ? m * (1.f - ay) * ax : 0.f;
        float w10 = (y1v && x0v) ? m * ay * (1.f - ax) : 0.f;
        float w11 = (y1v && x1v) ? m * ay * ax : 0.f;
        cw[p] = make_float4(w00, w01, w10, w11);
        coff[p] = make_ushort4((unsigned short)((iy0 << 6) + ix0),
                               (unsigned short)((iy0 << 6) + ix1),
                               (unsigned short)((iy1 << 6) + ix0),
                               (unsigned short)((iy1 << 6) + ix1));
    }
    __syncthreads();

    const int oct = t & 7, pq = t >> 3;      // 8 c-octs x 32 pixels
#pragma unroll
    for (int pp = 0; pp < 2; ++pp) {
        int p = (pp << 5) + pq;              // 0..63
        ushort4 o4 = coff[p];
        float4 w4 = cw[p];
        const int slot = (pq << 6) + ((oct ^ (pq & 7)) << 3);
#pragma unroll
        for (int cc = 0; cc < 4; ++cc) {
            int cb = (cc << 6) + (oct << 3);
            union { uint4 v; unsigned int u[4]; } A, B2, C2, D2;
            A.v  = *(const uint4*)(xb + ((int)o4.x << 8) + cb);
            B2.v = *(const uint4*)(xb + ((int)o4.y << 8) + cb);
            C2.v = *(const uint4*)(xb + ((int)o4.z << 8) + cb);
            D2.v = *(const uint4*)(xb + ((int)o4.w << 8) + cb);
            unsigned short o8[8];
#pragma unroll
            for (int j = 0; j < 4; ++j) {
                float al = __uint_as_float(A.u[j] << 16);
                float ah = __uint_as_float(A.u[j] & 0xffff0000u);
                float bl = __uint_as_float(B2.u[j] << 16);
                float bh = __uint_as_float(B2.u[j] & 0xffff0000u);
                float cl = __uint_as_float(C2.u[j] << 16);
                float ch = __uint_as_float(C2.u[j] & 0xffff0000u);
                float dl = __uint_as_float(D2.u[j] << 16);
                float dh = __uint_as_float(D2.u[j] & 0xffff0000u);
                float vl = w4.x * al + w4.y * bl + w4.z * cl + w4.w * dl;
                float vh = w4.x * ah + w4.y * bh + w4.z * ch + w4.w * dh;
                o8[2 * j]     = f32_to_bf16(vl);
                o8[2 * j + 1] = f32_to_bf16(vh);
            }
            size_t base = ((size_t)(b * 36 + (k << 2) + cc) * 128 + (pt << 1) + pp) * 2048;
            *(uint4*)(val + base + slot) = *(const uint4*)o8;
        }
    }
}

// ---------------------------------------------------------------------------
// Kernel 5: pure bf16 MFMA GEMM, 64 pixels/block, T4 counted-vmcnt pipeline.
// grid 256 (1 block/CU): b=(bid&7)>>1, tile64=(bid>>3)+((bid&1)<<5).
// 512 thr = 8 waves (4 o-rows x 2 p-cols), wave = 64o x 32p, acc[4][2].
// 3 LDS slots (120 KB), 2 chunks in flight; per-wave 5 VMEM/chunk ->
// steady-state s_waitcnt vmcnt(10), never 0 in the loop.
// ---------------------------------------------------------------------------
__global__ __launch_bounds__(512, 2) void dcn_gemm(
    const unsigned short* __restrict__ val, const unsigned short* __restrict__ wTs,
    const float* __restrict__ b_dcn, float* __restrict__ out) {
    __shared__ alignas(16) unsigned short wbuf[3][16384];   // 98304 B
    __shared__ alignas(16) unsigned short vbuf[3][4096];    // 24576 B

    const int t = threadIdx.x;
    const int bid = blockIdx.x;
    const int b = (bid & 7) >> 1;
    const int tile64 = (bid >> 3) + ((bid & 1) << 5);   // 0..63
    const int pix0 = tile64 << 6;

    const int wid = t >> 6, lane = t & 63;
    const int wo = wid >> 1, wp = wid & 1;
    const int m16 = lane & 15, kg = lane >> 4;

    // 5 VMEM instructions per wave per chunk (4 w + 1 v)
    auto stage = [&](int chunk, int slot) {
#pragma unroll
        for (int r = 0; r < 4; ++r) {
            int off16 = (r << 9) + t;   // 16B units, 0..2047
            const unsigned short* g = wTs + ((size_t)chunk << 14) + (off16 << 3);
            unsigned short* l = &wbuf[slot][off16 << 3];
            __builtin_amdgcn_global_load_lds(
                (const __attribute__((address_space(1))) unsigned int*)g,
                (__attribute__((address_space(3))) unsigned int*)l, 16, 0, 0);
        }
        const unsigned short* g = val + ((size_t)(b * 36 + chunk) * 128 + (tile64 << 1)) * 2048 + (t << 3);
        __builtin_amdgcn_global_load_lds(
            (const __attribute__((address_space(1))) unsigned int*)g,
            (__attribute__((address_space(3))) unsigned int*)&vbuf[slot][t << 3], 16, 0, 0);
    };

    f32x4 acc[4][2] = {};

    auto compute = [&](int slot) {
#pragma unroll
        for (int ks = 0; ks < 2; ++ks) {
            int s = (ks << 2) + kg;
            bf16x8 aF[4], bF[2];
#pragma unroll
            for (int i = 0; i < 4; ++i) {
                int o = (wo << 6) + (i << 4) + m16;
                aF[i] = *(const bf16x8*)&wbuf[slot][(o << 6) + ((s ^ (o & 7)) << 3)];
            }
#pragma unroll
            for (int j = 0; j < 2; ++j) {
                int p = (wp << 5) + (j << 4) + m16;   // 0..63
                int th = p >> 5, p32 = p & 31;
                bF[j] = *(const bf16x8*)&vbuf[slot][(th << 11) + (p32 << 6) + ((s ^ (p32 & 7)) << 3)];
            }
#pragma unroll
            for (int i = 0; i < 4; ++i)
#pragma unroll
                for (int j = 0; j < 2; ++j)
                    acc[i][j] = __builtin_amdgcn_mfma_f32_16x16x32_bf16(
                        aF[i], bF[j], acc[i][j], 0, 0, 0);
        }
    };

    // prologue: 3 chunks in flight (15 VMEM/wave)
    stage(0, 0);
    stage(1, 1);
    stage(2, 2);

    int cur = 0;
    for (int c = 0; c < 34; ++c) {
        // own chunk-c loads complete; chunks c+1, c+2 (10 VMEM) stay in flight
        asm volatile("s_waitcnt vmcnt(10)" ::: "memory");
        __builtin_amdgcn_s_barrier();          // all waves' chunk-c DMA landed
        asm volatile("" ::: "memory");
        compute(cur);
        asm volatile("" ::: "memory");
        __builtin_amdgcn_s_barrier();          // all waves done reading slot cur
        stage(c + 3, cur);                     // (c+3)%3 == cur
        cur = (cur == 2) ? 0 : cur + 1;
    }
    // c = 34: only chunk 35 (5 VMEM) still in flight
    asm volatile("s_waitcnt vmcnt(5)" ::: "memory");
    __builtin_amdgcn_s_barrier();
    asm volatile("" ::: "memory");
    compute(cur);
    cur = (cur == 2) ? 0 : cur + 1;
    // c = 35: drain
    asm volatile("s_waitcnt vmcnt(0)" ::: "memory");
    __builtin_amdgcn_s_barrier();
    asm volatile("" ::: "memory");
    compute(cur);

    // epilogue: C/D layout col=lane&15 (pixel), row=(lane>>4)*4+r (o within 16)
#pragma unroll
    for (int i = 0; i < 4; ++i) {
        int ob = (wo << 6) + (i << 4) + (kg << 2);
#pragma unroll
        for (int j = 0; j < 2; ++j) {
            int p = pix0 + (wp << 5) + (j << 4) + m16;
#pragma unroll
            for (int r = 0; r < 4; ++r) {
                int oo = ob + r;
                out[(((size_t)(b << 8) + oo) << 12) + p] = acc[i][j][r] + b_dcn[oo];
            }
        }
    }
}

// ---------------------------------------------------------------------------
extern "C" void kernel_launch(void* const* d_in, const int* in_sizes, int n_in,
                              void* d_out, int out_size, void* d_ws, size_t ws_size,
                              hipStream_t stream) {
    const float* x      = (const float*)d_in[0];
    const float* w_off  = (const float*)d_in[1];
    const float* b_off  = (const float*)d_in[2];
    const float* w_mask = (const float*)d_in[3];
    const float* b_mask = (const float*)d_in[4];
    const float* w_dcn  = (const float*)d_in[5];
    const float* b_dcn  = (const float*)d_in[6];
    float* out = (float*)d_out;

    float* ws = (float*)d_ws;
    float* offmask = ws;                                       //  1.77 MB
    unsigned short* xTh = (unsigned short*)(offmask + (size_t)B_ * NCH_ * HW_); // 8.39 MB
    unsigned short* wTs = xTh + ((size_t)B_ * HW_ * C_);       //  1.18 MB
    unsigned short* wCs = wTs + (size_t)36 * 16384;            //  0.15 MB
    unsigned short* val = wCs + (size_t)36 * 2048;             // 75.5 MB
    // total ~87 MB of d_ws

    transpose_x<<<dim3(4096), dim3(256), 0, stream>>>(x, xTh);
    prep_weights<<<dim3(288), dim3(256), 0, stream>>>(w_dcn, w_off, w_mask, wTs, wCs);
    conv_mfma<<<dim3(512), dim3(256), 0, stream>>>(xTh, wCs, b_off, b_mask, offmask);
    produce_val<<<dim3(2304), dim3(256), 0, stream>>>(xTh, offmask, val);
    dcn_gemm<<<dim3(256), dim3(512), 0, stream>>>(val, wTs, b_dcn, out);
}

// Round 10
// 78.885 us; speedup vs baseline: 4.9300x; 1.1085x over previous
//
#include <hip/hip_runtime.h>
#include <math.h>

// Problem constants
#define B_ 4
#define C_ 256
#define CO_ 256
#define H_ 64
#define W_ 64
#define HW_ 4096
#define KK_ 9   // 3x3 kernel positions
#define NCH_ 27 // 18 offset + 9 mask channels

typedef __attribute__((ext_vector_type(8))) short bf16x8;
typedef __attribute__((ext_vector_type(4))) float f32x4;

__device__ inline unsigned short f32_to_bf16(float f) {
    unsigned int u = __float_as_uint(f);
    unsigned int r = (u + 0x7FFFu + ((u >> 16) & 1u)) >> 16;  // RNE
    return (unsigned short)r;
}

// ---------------------------------------------------------------------------
// Kernel 1: prep_all = transpose_x (bid<4096) + prep_weights (bid>=4096).
// transpose: x NCHW f32 -> NHWC bf16. prep: weights -> bf16 pre-swizzled
// chunks; pos = (o<<6) + (((ck>>3)^(o&7))<<3) + (ck&7).
// ---------------------------------------------------------------------------
__global__ void prep_all(const float* __restrict__ x, unsigned short* __restrict__ xTh,
                         const float* __restrict__ w_dcn, const float* __restrict__ w_off,
                         const float* __restrict__ w_mask,
                         unsigned short* __restrict__ wTs, unsigned short* __restrict__ wCs) {
    __shared__ float tile[32][33];
    __shared__ float lw[2304];
    const int t = threadIdx.x;
    const int bid = blockIdx.x;
    if (bid < 4096) {
        const int tx = t & 31, ty = t >> 5;
        const int b = bid >> 10;
        const int rem = bid & 1023;
        const int c0 = (rem >> 7) << 5;
        const int hw0 = (rem & 127) << 5;
        const float* xb = x + ((size_t)b << 20);
        unsigned short* xTb = xTh + ((size_t)b << 20);
#pragma unroll
        for (int r = 0; r < 4; ++r) {
            int row = ty + (r << 3);
            tile[row][tx] = xb[((size_t)(c0 + row) << 12) + hw0 + tx];
        }
        __syncthreads();
#pragma unroll
        for (int r = 0; r < 4; ++r) {
            int row = ty + (r << 3);
            xTb[((size_t)(hw0 + row) << 8) + c0 + tx] = f32_to_bf16(tile[tx][row]);
        }
    } else if (bid < 4352) {
        const int o = bid - 4096;
        for (int e = t; e < 2304; e += 256) lw[e] = w_dcn[(size_t)o * 2304 + e];
        __syncthreads();
        for (int e = t; e < 2304; e += 256) {
            int k = e >> 8, c = e & 255;
            int chunk = (k << 2) + (c >> 6), ck = c & 63;
            int pos = (o << 6) + (((ck >> 3) ^ (o & 7)) << 3) + (ck & 7);
            wTs[(size_t)chunk * 16384 + pos] = f32_to_bf16(lw[c * 9 + k]);
        }
    } else {
        const int ch = bid - 4352;  // 0..31
        const float* src = (ch < 18) ? w_off + (size_t)ch * 2304
                         : (ch < NCH_) ? w_mask + (size_t)(ch - 18) * 2304
                         : nullptr;
        for (int e = t; e < 2304; e += 256) lw[e] = src ? src[e] : 0.f;
        __syncthreads();
        for (int e = t; e < 2304; e += 256) {
            int k = e >> 8, c = e & 255;
            int chunk = (k << 2) + (c >> 6), ck = c & 63;
            int pos = (ch << 6) + (((ck >> 3) ^ (ch & 7)) << 3) + (ck & 7);
            wCs[(size_t)chunk * 2048 + pos] = f32_to_bf16(lw[c * 9 + k]);
        }
    }
}

// ---------------------------------------------------------------------------
// Kernel 2: offset+mask 3x3 conv via bf16 MFMA, 32 pixels per block.
// grid 512 (2 blocks/CU): b=(bid&7)>>1, ph=bid&1, hh=bid>>3.
// ---------------------------------------------------------------------------
__global__ __launch_bounds__(256, 2) void conv_mfma(
    const unsigned short* __restrict__ xTh, const unsigned short* __restrict__ wCs,
    const float* __restrict__ b_off, const float* __restrict__ b_mask,
    float* __restrict__ offmask) {
    __shared__ alignas(16) unsigned short wlds[2][2048];   //  8 KB
    __shared__ alignas(16) unsigned short xlds[2][2048];   //  8 KB
    const int t = threadIdx.x;
    const int bid = blockIdx.x;
    const int b = (bid & 7) >> 1;
    const int ph = bid & 1;
    const int hh = bid >> 3;
    const unsigned short* xb = xTh + ((size_t)b << 20);

    auto stage_w = [&](int chunk, int buf) {
        const unsigned short* g = wCs + ((size_t)chunk << 11) + (t << 3);
        __builtin_amdgcn_global_load_lds(
            (const __attribute__((address_space(1))) unsigned int*)g,
            (__attribute__((address_space(3))) unsigned int*)&wlds[buf][t << 3], 16, 0, 0);
    };

    auto stage_x = [&](int chunk, int buf) {
        int k = chunk >> 2, cc = chunk & 3;
        int ki = k / 3, kj = k % 3;
        int py = hh + ki - 1;
        int p = t >> 3, cs = t & 7;           // 32 p x 8 c-octs = 256
        int px = (ph << 5) + p + kj - 1;
        uint4 u = make_uint4(0u, 0u, 0u, 0u);
        if (py >= 0 && py < H_ && px >= 0 && px < W_)
            u = *(const uint4*)(xb + (((size_t)((py << 6) + px)) << 8) + (cc << 6) + (cs << 3));
        *(uint4*)&xlds[buf][(p << 6) + ((cs ^ (p & 7)) << 3)] = u;
    };

    const int wid = t >> 6, lane = t & 63;
    const int wc = wid >> 1, wp = wid & 1;
    const int m16 = lane & 15, kg = lane >> 4;
    f32x4 acc = {};

    stage_w(0, 0);
    stage_x(0, 0);
    __syncthreads();

    for (int chunk = 0; chunk < 36; ++chunk) {
        int cur = chunk & 1, nxt = cur ^ 1;
        if (chunk < 35) { stage_w(chunk + 1, nxt); stage_x(chunk + 1, nxt); }
#pragma unroll
        for (int ks = 0; ks < 2; ++ks) {
            int s = (ks << 2) + kg;
            int o = (wc << 4) + m16;
            bf16x8 a = *(const bf16x8*)&wlds[cur][(o << 6) + ((s ^ (o & 7)) << 3)];
            int p = (wp << 4) + m16;
            bf16x8 bf = *(const bf16x8*)&xlds[cur][(p << 6) + ((s ^ (p & 7)) << 3)];
            acc = __builtin_amdgcn_mfma_f32_16x16x32_bf16(a, bf, acc, 0, 0, 0);
        }
        __syncthreads();
    }

    const int pix = (hh << 6) + (ph << 5) + (wp << 4) + m16;
#pragma unroll
    for (int r = 0; r < 4; ++r) {
        int ch = (wc << 4) + (kg << 2) + r;
        if (ch < NCH_) {
            float bias = (ch < 18) ? b_off[ch] : b_mask[ch - 18];
            offmask[(((size_t)b * NCH_ + ch) << 12) + pix] = acc[r] + bias;
        }
    }
}

// ---------------------------------------------------------------------------
// Kernel 3: fused deformable-sample + bf16 MFMA GEMM, T4/T14 pipeline.
// grid 256 (1 block/CU): b=(bid&7)>>1, tile64=(bid>>3)+((bid&1)<<5).
// 512 thr = 8 waves (4 o x 2 p), wave = 64o x 32p, acc[4][2].
// Per half-chunk: barA | gather(c+1)->regs + stage_w(c+2) DMA |
// vmcnt(12) | finish v(c)+ds_write | lgkm0+barB | MFMA(c).
// Weights 3-slot (WAR via barA); vbuf single (WAR via barA).
// LDS: 9216 + 4608 + 98304 + 8192 = 120320 B.
// ---------------------------------------------------------------------------
__global__ __launch_bounds__(512, 1) void dcn_fused(
    const unsigned short* __restrict__ xTh, const float* __restrict__ offmask,
    const unsigned short* __restrict__ wTs, const float* __restrict__ b_dcn,
    float* __restrict__ out) {
    __shared__ float4 cw[576];                              //  9216 B
    __shared__ ushort4 coff[576];                           //  4608 B
    __shared__ alignas(16) unsigned short wbuf[3][16384];   // 98304 B
    __shared__ alignas(16) unsigned short vbuf[4096];       //  8192 B

    const int t = threadIdx.x;
    const int bid = blockIdx.x;
    const int b = (bid & 7) >> 1;
    const int tile64 = (bid >> 3) + ((bid & 1) << 5);   // 0..63
    const int pix0 = tile64 << 6;
    const unsigned short* xb = xTh + ((size_t)b << 20);
    const float* omb = offmask + (((size_t)b * NCH_) << 12);

    // ---- coords: 9 k x 64 p bilinear weights (mask folded) + corner pix ids
    for (int e = t; e < 576; e += 512) {
        int k = e >> 6, p = e & 63;
        int pix = pix0 + p;
        int hh = pix >> 6, ww = pix & 63;
        float dy = omb[((size_t)(2 * k) << 12) + pix];
        float dx = omb[((size_t)(2 * k + 1) << 12) + pix];
        float ml = omb[((size_t)(18 + k) << 12) + pix];
        float m = 1.f / (1.f + __expf(-ml));
        float py = (float)(hh - 1 + (k / 3)) + dy;
        float px = (float)(ww - 1 + (k % 3)) + dx;
        float fy0 = floorf(py), fx0 = floorf(px);
        float ay = py - fy0, ax = px - fx0;
        bool y0v = (fy0 >= 0.f) && (fy0 <= 63.f);
        bool y1v = (fy0 >= -1.f) && (fy0 <= 62.f);
        bool x0v = (fx0 >= 0.f) && (fx0 <= 63.f);
        bool x1v = (fx0 >= -1.f) && (fx0 <= 62.f);
        int y0 = (int)fy0, x0 = (int)fx0;
        int iy0 = min(max(y0, 0), 63), iy1 = min(max(y0 + 1, 0), 63);
        int ix0 = min(max(x0, 0), 63), ix1 = min(max(x0 + 1, 0), 63);
        float w00 = (y0v && x0v) ? m * (1.f - ay) * (1.f - ax) : 0.f;
        float w01 = (y0v && x1v) ? m * (1.f - ay) * ax : 0.f;
        float w10 = (y1v && x0v) ? m * ay * (1.f - ax) : 0.f;
        float w11 = (y1v && x1v) ? m * ay * ax : 0.f;
        cw[e] = make_float4(w00, w01, w10, w11);
        coff[e] = make_ushort4((unsigned short)((iy0 << 6) + ix0),
                               (unsigned short)((iy0 << 6) + ix1),
                               (unsigned short)((iy1 << 6) + ix0),
                               (unsigned short)((iy1 << 6) + ix1));
    }

    const int oct = t & 7, pq = t >> 3;   // producer: 8 c-octs x 64 pixels
    const int wid = t >> 6, lane = t & 63;
    const int wo = wid >> 1, wp = wid & 1;
    const int m16 = lane & 15, kg = lane >> 4;

    auto stage_w = [&](int chunk, int slot) {
#pragma unroll
        for (int r = 0; r < 4; ++r) {
            int off16 = (r << 9) + t;   // 16B units
            const unsigned short* g = wTs + ((size_t)chunk << 14) + (off16 << 3);
            __builtin_amdgcn_global_load_lds(
                (const __attribute__((address_space(1))) unsigned int*)g,
                (__attribute__((address_space(3))) unsigned int*)&wbuf[slot][off16 << 3], 16, 0, 0);
        }
    };

    auto gather = [&](int chunk, uint4* g) {
        int k = chunk >> 2, cc = chunk & 3;
        ushort4 o4 = coff[(k << 6) + pq];
        const unsigned short* cb = xb + (cc << 6) + (oct << 3);
        g[0] = *(const uint4*)(cb + ((int)o4.x << 8));
        g[1] = *(const uint4*)(cb + ((int)o4.y << 8));
        g[2] = *(const uint4*)(cb + ((int)o4.z << 8));
        g[3] = *(const uint4*)(cb + ((int)o4.w << 8));
    };

    auto finish = [&](int chunk, const uint4* g) {
        int k = chunk >> 2;
        float4 w4 = cw[(k << 6) + pq];
        union { uint4 v; unsigned int u[4]; } A, B2, C2, D2;
        A.v = g[0]; B2.v = g[1]; C2.v = g[2]; D2.v = g[3];
        unsigned short o8[8];
#pragma unroll
        for (int j = 0; j < 4; ++j) {
            float al = __uint_as_float(A.u[j] << 16);
            float ah = __uint_as_float(A.u[j] & 0xffff0000u);
            float bl = __uint_as_float(B2.u[j] << 16);
            float bh = __uint_as_float(B2.u[j] & 0xffff0000u);
            float cl = __uint_as_float(C2.u[j] << 16);
            float ch = __uint_as_float(C2.u[j] & 0xffff0000u);
            float dl = __uint_as_float(D2.u[j] << 16);
            float dh = __uint_as_float(D2.u[j] & 0xffff0000u);
            float vl = w4.x * al + w4.y * bl + w4.z * cl + w4.w * dl;
            float vh = w4.x * ah + w4.y * bh + w4.z * ch + w4.w * dh;
            o8[2 * j]     = f32_to_bf16(vl);
            o8[2 * j + 1] = f32_to_bf16(vh);
        }
        *(uint4*)&vbuf[(pq << 6) + ((oct ^ (pq & 7)) << 3)] = *(const uint4*)o8;
    };

    f32x4 acc[4][2] = {};

    auto compute = [&](int slot) {
#pragma unroll
        for (int ks = 0; ks < 2; ++ks) {
            int s = (ks << 2) + kg;
            bf16x8 aF[4], bF[2];
#pragma unroll
            for (int i = 0; i < 4; ++i) {
                int o = (wo << 6) + (i << 4) + m16;
                aF[i] = *(const bf16x8*)&wbuf[slot][(o << 6) + ((s ^ (o & 7)) << 3)];
            }
#pragma unroll
            for (int j = 0; j < 2; ++j) {
                int p = (wp << 5) + (j << 4) + m16;   // 0..63
                bF[j] = *(const bf16x8*)&vbuf[(p << 6) + ((s ^ (p & 7)) << 3)];
            }
#pragma unroll
            for (int i = 0; i < 4; ++i)
#pragma unroll
                for (int j = 0; j < 2; ++j)
                    acc[i][j] = __builtin_amdgcn_mfma_f32_16x16x32_bf16(
                        aF[i], bF[j], acc[i][j], 0, 0, 0);
        }
    };

    uint4 gA[4], gB[4];

    __syncthreads();            // coords visible
    // prologue: issue order [g(0), w(0), w(1)]
    gather(0, gA);
    stage_w(0, 0);
    stage_w(1, 1);

    // Per half-chunk CUR (consume GCUR, prefetch into GNXT):
    //   barA | gather(CUR+1) stage_w(CUR+2) | vmcnt(NW) | finish | lgkm0 barB | mfma
    // NW=12 keeps [w(CUR+1), g(CUR+1), w(CUR+2)] in flight; tail: 8 then 0.
#define HALF(CUR, GCUR, GNXT, NW)                                        \
    __builtin_amdgcn_s_barrier();                                        \
    asm volatile("" ::: "memory");                                       \
    if ((CUR) + 1 < 36) gather((CUR) + 1, GNXT);                         \
    if ((CUR) + 2 < 36) stage_w((CUR) + 2, ((CUR) + 2) % 3);             \
    asm volatile("s_waitcnt vmcnt(" #NW ")" ::: "memory");               \
    finish((CUR), GCUR);                                                 \
    asm volatile("s_waitcnt lgkmcnt(0)" ::: "memory");                   \
    __builtin_amdgcn_s_barrier();                                        \
    asm volatile("" ::: "memory");                                       \
    compute((CUR) % 3);

    for (int c = 0; c < 34; c += 2) {
        HALF(c, gA, gB, 12)
        HALF(c + 1, gB, gA, 12)
    }
    HALF(34, gA, gB, 8)
    HALF(35, gB, gA, 0)
#undef HALF

    // epilogue: C/D layout col=lane&15 (pixel), row=(lane>>4)*4+r (o within 16)
#pragma unroll
    for (int i = 0; i < 4; ++i) {
        int ob = (wo << 6) + (i << 4) + (kg << 2);
#pragma unroll
        for (int j = 0; j < 2; ++j) {
            int p = pix0 + (wp << 5) + (j << 4) + m16;
#pragma unroll
            for (int r = 0; r < 4; ++r) {
                int oo = ob + r;
                out[(((size_t)(b << 8) + oo) << 12) + p] = acc[i][j][r] + b_dcn[oo];
            }
        }
    }
}

// ---------------------------------------------------------------------------
extern "C" void kernel_launch(void* const* d_in, const int* in_sizes, int n_in,
                              void* d_out, int out_size, void* d_ws, size_t ws_size,
                              hipStream_t stream) {
    const float* x      = (const float*)d_in[0];
    const float* w_off  = (const float*)d_in[1];
    const float* b_off  = (const float*)d_in[2];
    const float* w_mask = (const float*)d_in[3];
    const float* b_mask = (const float*)d_in[4];
    const float* w_dcn  = (const float*)d_in[5];
    const float* b_dcn  = (const float*)d_in[6];
    float* out = (float*)d_out;

    float* ws = (float*)d_ws;
    float* offmask = ws;                                       //  1.77 MB
    unsigned short* xTh = (unsigned short*)(offmask + (size_t)B_ * NCH_ * HW_); // 8.39 MB
    unsigned short* wTs = xTh + ((size_t)B_ * HW_ * C_);       //  1.18 MB
    unsigned short* wCs = wTs + (size_t)36 * 16384;            //  0.15 MB
    // total ~11.5 MB of d_ws

    prep_all<<<dim3(4384), dim3(256), 0, stream>>>(x, xTh, w_dcn, w_off, w_mask, wTs, wCs);
    conv_mfma<<<dim3(512), dim3(256), 0, stream>>>(xTh, wCs, b_off, b_mask, offmask);
    dcn_fused<<<dim3(256), dim3(512), 0, stream>>>(xTh, offmask, wTs, b_dcn, out);
}

// Round 11
// 73.620 us; speedup vs baseline: 5.2825x; 1.0715x over previous
//
#include <hip/hip_runtime.h>
#include <math.h>

// Problem constants
#define B_ 4
#define C_ 256
#define CO_ 256
#define H_ 64
#define W_ 64
#define HW_ 4096
#define KK_ 9   // 3x3 kernel positions
#define NCH_ 27 // 18 offset + 9 mask channels

typedef __attribute__((ext_vector_type(8))) short bf16x8;
typedef __attribute__((ext_vector_type(4))) float f32x4;

__device__ inline unsigned short f32_to_bf16(float f) {
    unsigned int u = __float_as_uint(f);
    unsigned int r = (u + 0x7FFFu + ((u >> 16) & 1u)) >> 16;  // RNE
    return (unsigned short)r;
}

// ---------------------------------------------------------------------------
// Kernel 1: prep_all = transpose_x (bid<4096) + prep_weights (bid>=4096).
// ---------------------------------------------------------------------------
__global__ void prep_all(const float* __restrict__ x, unsigned short* __restrict__ xTh,
                         const float* __restrict__ w_dcn, const float* __restrict__ w_off,
                         const float* __restrict__ w_mask,
                         unsigned short* __restrict__ wTs, unsigned short* __restrict__ wCs) {
    __shared__ float tile[32][33];
    __shared__ float lw[2304];
    const int t = threadIdx.x;
    const int bid = blockIdx.x;
    if (bid < 4096) {
        const int tx = t & 31, ty = t >> 5;
        const int b = bid >> 10;
        const int rem = bid & 1023;
        const int c0 = (rem >> 7) << 5;
        const int hw0 = (rem & 127) << 5;
        const float* xb = x + ((size_t)b << 20);
        unsigned short* xTb = xTh + ((size_t)b << 20);
#pragma unroll
        for (int r = 0; r < 4; ++r) {
            int row = ty + (r << 3);
            tile[row][tx] = xb[((size_t)(c0 + row) << 12) + hw0 + tx];
        }
        __syncthreads();
#pragma unroll
        for (int r = 0; r < 4; ++r) {
            int row = ty + (r << 3);
            xTb[((size_t)(hw0 + row) << 8) + c0 + tx] = f32_to_bf16(tile[tx][row]);
        }
    } else if (bid < 4352) {
        const int o = bid - 4096;
        for (int e = t; e < 2304; e += 256) lw[e] = w_dcn[(size_t)o * 2304 + e];
        __syncthreads();
        for (int e = t; e < 2304; e += 256) {
            int k = e >> 8, c = e & 255;
            int chunk = (k << 2) + (c >> 6), ck = c & 63;
            int pos = (o << 6) + (((ck >> 3) ^ (o & 7)) << 3) + (ck & 7);
            wTs[(size_t)chunk * 16384 + pos] = f32_to_bf16(lw[c * 9 + k]);
        }
    } else {
        const int ch = bid - 4352;  // 0..31
        const float* src = (ch < 18) ? w_off + (size_t)ch * 2304
                         : (ch < NCH_) ? w_mask + (size_t)(ch - 18) * 2304
                         : nullptr;
        for (int e = t; e < 2304; e += 256) lw[e] = src ? src[e] : 0.f;
        __syncthreads();
        for (int e = t; e < 2304; e += 256) {
            int k = e >> 8, c = e & 255;
            int chunk = (k << 2) + (c >> 6), ck = c & 63;
            int pos = (ch << 6) + (((ck >> 3) ^ (ch & 7)) << 3) + (ck & 7);
            wCs[(size_t)chunk * 2048 + pos] = f32_to_bf16(lw[c * 9 + k]);
        }
    }
}

// ---------------------------------------------------------------------------
// Kernel 2: offset+mask 3x3 conv via bf16 MFMA, 32 pixels per block.
// grid 512 (2 blocks/CU): b=(bid&7)>>1, ph=bid&1, hh=bid>>3.
// ---------------------------------------------------------------------------
__global__ __launch_bounds__(256, 2) void conv_mfma(
    const unsigned short* __restrict__ xTh, const unsigned short* __restrict__ wCs,
    const float* __restrict__ b_off, const float* __restrict__ b_mask,
    float* __restrict__ offmask) {
    __shared__ alignas(16) unsigned short wlds[2][2048];   //  8 KB
    __shared__ alignas(16) unsigned short xlds[2][2048];   //  8 KB
    const int t = threadIdx.x;
    const int bid = blockIdx.x;
    const int b = (bid & 7) >> 1;
    const int ph = bid & 1;
    const int hh = bid >> 3;
    const unsigned short* xb = xTh + ((size_t)b << 20);

    auto stage_w = [&](int chunk, int buf) {
        const unsigned short* g = wCs + ((size_t)chunk << 11) + (t << 3);
        __builtin_amdgcn_global_load_lds(
            (const __attribute__((address_space(1))) unsigned int*)g,
            (__attribute__((address_space(3))) unsigned int*)&wlds[buf][t << 3], 16, 0, 0);
    };

    auto stage_x = [&](int chunk, int buf) {
        int k = chunk >> 2, cc = chunk & 3;
        int ki = k / 3, kj = k % 3;
        int py = hh + ki - 1;
        int p = t >> 3, cs = t & 7;           // 32 p x 8 c-octs = 256
        int px = (ph << 5) + p + kj - 1;
        uint4 u = make_uint4(0u, 0u, 0u, 0u);
        if (py >= 0 && py < H_ && px >= 0 && px < W_)
            u = *(const uint4*)(xb + (((size_t)((py << 6) + px)) << 8) + (cc << 6) + (cs << 3));
        *(uint4*)&xlds[buf][(p << 6) + ((cs ^ (p & 7)) << 3)] = u;
    };

    const int wid = t >> 6, lane = t & 63;
    const int wc = wid >> 1, wp = wid & 1;
    const int m16 = lane & 15, kg = lane >> 4;
    f32x4 acc = {};

    stage_w(0, 0);
    stage_x(0, 0);
    __syncthreads();

    for (int chunk = 0; chunk < 36; ++chunk) {
        int cur = chunk & 1, nxt = cur ^ 1;
        if (chunk < 35) { stage_w(chunk + 1, nxt); stage_x(chunk + 1, nxt); }
#pragma unroll
        for (int ks = 0; ks < 2; ++ks) {
            int s = (ks << 2) + kg;
            int o = (wc << 4) + m16;
            bf16x8 a = *(const bf16x8*)&wlds[cur][(o << 6) + ((s ^ (o & 7)) << 3)];
            int p = (wp << 4) + m16;
            bf16x8 bf = *(const bf16x8*)&xlds[cur][(p << 6) + ((s ^ (p & 7)) << 3)];
            acc = __builtin_amdgcn_mfma_f32_16x16x32_bf16(a, bf, acc, 0, 0, 0);
        }
        __syncthreads();
    }

    const int pix = (hh << 6) + (ph << 5) + (wp << 4) + m16;
#pragma unroll
    for (int r = 0; r < 4; ++r) {
        int ch = (wc << 4) + (kg << 2) + r;
        if (ch < NCH_) {
            float bias = (ch < 18) ? b_off[ch] : b_mask[ch - 18];
            offmask[(((size_t)b * NCH_ + ch) << 12) + pix] = acc[r] + bias;
        }
    }
}

// ---------------------------------------------------------------------------
// Kernel 3: fused sample + bf16 MFMA GEMM, K-SPLIT x2 over c, 2 blocks/CU.
// grid 512: b=(bid&7)>>1, half=bid&1, tile64=bid>>3. Block computes the
// partial over cc in {2*half, 2*half+1} (18 chunks of 64 ck) into part[].
// 512 thr = 8 waves (4o x 2p), wave 64o x 32p, acc[4][2].
// Per chunk c: barA | gather(c+1)->regs, stage_w(c+1) DMA | vmcnt(8) |
// finish v(c)+ds_write | lgkm0 barB | MFMA(c). wbuf 2-slot, vbuf single.
// LDS: 4608(cw bf16) + 2304(coff u8) + 65536 + 8192 = 80640 B -> 2/CU.
// ---------------------------------------------------------------------------
__global__ __launch_bounds__(512, 4) void dcn_fused(
    const unsigned short* __restrict__ xTh, const float* __restrict__ offmask,
    const unsigned short* __restrict__ wTs, float* __restrict__ part) {
    __shared__ ushort4 cwh[576];                            //  4608 B
    __shared__ uchar4 coffb[576];                           //  2304 B
    __shared__ alignas(16) unsigned short wbuf[2][16384];   // 65536 B
    __shared__ alignas(16) unsigned short vbuf[4096];       //  8192 B

    const int t = threadIdx.x;
    const int bid = blockIdx.x;
    const int b = (bid & 7) >> 1;
    const int half = bid & 1;
    const int tile64 = bid >> 3;        // 0..63
    const int pix0 = tile64 << 6;
    const unsigned short* xb = xTh + ((size_t)b << 20);
    const float* omb = offmask + (((size_t)b * NCH_) << 12);

    // ---- coords: 9 k x 64 p: bilinear weights (mask folded, bf16) + corners
    for (int e = t; e < 576; e += 512) {
        int k = e >> 6, p = e & 63;
        int pix = pix0 + p;
        int hh = pix >> 6, ww = pix & 63;
        float dy = omb[((size_t)(2 * k) << 12) + pix];
        float dx = omb[((size_t)(2 * k + 1) << 12) + pix];
        float ml = omb[((size_t)(18 + k) << 12) + pix];
        float m = 1.f / (1.f + __expf(-ml));
        float py = (float)(hh - 1 + (k / 3)) + dy;
        float px = (float)(ww - 1 + (k % 3)) + dx;
        float fy0 = floorf(py), fx0 = floorf(px);
        float ay = py - fy0, ax = px - fx0;
        bool y0v = (fy0 >= 0.f) && (fy0 <= 63.f);
        bool y1v = (fy0 >= -1.f) && (fy0 <= 62.f);
        bool x0v = (fx0 >= 0.f) && (fx0 <= 63.f);
        bool x1v = (fx0 >= -1.f) && (fx0 <= 62.f);
        int y0 = (int)fy0, x0 = (int)fx0;
        int iy0 = min(max(y0, 0), 63), iy1 = min(max(y0 + 1, 0), 63);
        int ix0 = min(max(x0, 0), 63), ix1 = min(max(x0 + 1, 0), 63);
        float w00 = (y0v && x0v) ? m * (1.f - ay) * (1.f - ax) : 0.f;
        float w01 = (y0v && x1v) ? m * (1.f - ay) * ax : 0.f;
        float w10 = (y1v && x0v) ? m * ay * (1.f - ax) : 0.f;
        float w11 = (y1v && x1v) ? m * ay * ax : 0.f;
        cwh[e] = make_ushort4(f32_to_bf16(w00), f32_to_bf16(w01),
                              f32_to_bf16(w10), f32_to_bf16(w11));
        coffb[e] = make_uchar4((unsigned char)iy0, (unsigned char)ix0,
                               (unsigned char)iy1, (unsigned char)ix1);
    }

    const int oct = t & 7, pq = t >> 3;   // producer: 8 c-octs x 64 pixels
    const int wid = t >> 6, lane = t & 63;
    const int wo = wid >> 1, wp = wid & 1;
    const int m16 = lane & 15, kg = lane >> 4;
    const int vslot = (pq << 6) + ((oct ^ (pq & 7)) << 3);

    // local chunk c (0..17) -> global chunk gc = (c>>1)*4 + half*2 + (c&1)
    auto stage_w = [&](int c, int slot) {
        int gc = ((c >> 1) << 2) + (half << 1) + (c & 1);
#pragma unroll
        for (int r = 0; r < 4; ++r) {
            int off16 = (r << 9) + t;   // 16B units
            const unsigned short* g = wTs + ((size_t)gc << 14) + (off16 << 3);
            __builtin_amdgcn_global_load_lds(
                (const __attribute__((address_space(1))) unsigned int*)g,
                (__attribute__((address_space(3))) unsigned int*)&wbuf[slot][off16 << 3], 16, 0, 0);
        }
    };

    auto gather = [&](int c, uint4* g) {
        int k = c >> 1, cc = (half << 1) + (c & 1);
        uchar4 q = coffb[(k << 6) + pq];
        const unsigned short* cb = xb + (cc << 6) + (oct << 3);
        g[0] = *(const uint4*)(cb + ((((int)q.x << 6) + q.y) << 8));
        g[1] = *(const uint4*)(cb + ((((int)q.x << 6) + q.w) << 8));
        g[2] = *(const uint4*)(cb + ((((int)q.z << 6) + q.y) << 8));
        g[3] = *(const uint4*)(cb + ((((int)q.z << 6) + q.w) << 8));
    };

    auto finish = [&](int c, const uint4* g) {
        int k = c >> 1;
        ushort4 wv = cwh[(k << 6) + pq];
        float w0 = __uint_as_float((unsigned int)wv.x << 16);
        float w1 = __uint_as_float((unsigned int)wv.y << 16);
        float w2 = __uint_as_float((unsigned int)wv.z << 16);
        float w3 = __uint_as_float((unsigned int)wv.w << 16);
        union { uint4 v; unsigned int u[4]; } A, B2, C2, D2;
        A.v = g[0]; B2.v = g[1]; C2.v = g[2]; D2.v = g[3];
        unsigned int o4[4];
#pragma unroll
        for (int j = 0; j < 4; ++j) {
            float al = __uint_as_float(A.u[j] << 16);
            float ah = __uint_as_float(A.u[j] & 0xffff0000u);
            float bl = __uint_as_float(B2.u[j] << 16);
            float bh = __uint_as_float(B2.u[j] & 0xffff0000u);
            float cl = __uint_as_float(C2.u[j] << 16);
            float ch = __uint_as_float(C2.u[j] & 0xffff0000u);
            float dl = __uint_as_float(D2.u[j] << 16);
            float dh = __uint_as_float(D2.u[j] & 0xffff0000u);
            float vl = w0 * al + w1 * bl + w2 * cl + w3 * dl;
            float vh = w0 * ah + w1 * bh + w2 * ch + w3 * dh;
            unsigned int pk;
            asm("v_cvt_pk_bf16_f32 %0, %1, %2" : "=v"(pk) : "v"(vl), "v"(vh));
            o4[j] = pk;
        }
        *(uint4*)&vbuf[vslot] = make_uint4(o4[0], o4[1], o4[2], o4[3]);
    };

    f32x4 acc[4][2] = {};

    auto compute = [&](int slot) {
#pragma unroll
        for (int ks = 0; ks < 2; ++ks) {
            int s = (ks << 2) + kg;
            bf16x8 aF[4], bF[2];
#pragma unroll
            for (int i = 0; i < 4; ++i) {
                int o = (wo << 6) + (i << 4) + m16;
                aF[i] = *(const bf16x8*)&wbuf[slot][(o << 6) + ((s ^ (o & 7)) << 3)];
            }
#pragma unroll
            for (int j = 0; j < 2; ++j) {
                int p = (wp << 5) + (j << 4) + m16;   // 0..63
                bF[j] = *(const bf16x8*)&vbuf[(p << 6) + ((s ^ (p & 7)) << 3)];
            }
#pragma unroll
            for (int i = 0; i < 4; ++i)
#pragma unroll
                for (int j = 0; j < 2; ++j)
                    acc[i][j] = __builtin_amdgcn_mfma_f32_16x16x32_bf16(
                        aF[i], bF[j], acc[i][j], 0, 0, 0);
        }
    };

    uint4 gA[4], gB[4];

    __syncthreads();            // coords visible
    gather(0, gA);
    stage_w(0, 0);

    // Steady: 8 VMEM/wave/chunk in flight (g(c+1) 4 + w(c+1) 4) -> vmcnt(8).
#define HALFSTEP(CUR, GCUR, GNXT, NW)                                    \
    __builtin_amdgcn_s_barrier();                                        \
    asm volatile("" ::: "memory");                                       \
    if ((CUR) + 1 < 18) { gather((CUR) + 1, GNXT); stage_w((CUR) + 1, ((CUR) + 1) & 1); } \
    asm volatile("s_waitcnt vmcnt(" #NW ")" ::: "memory");               \
    finish((CUR), GCUR);                                                 \
    asm volatile("s_waitcnt lgkmcnt(0)" ::: "memory");                   \
    __builtin_amdgcn_s_barrier();                                        \
    asm volatile("" ::: "memory");                                       \
    compute((CUR) & 1);

    for (int c = 0; c < 16; c += 2) {
        HALFSTEP(c, gA, gB, 8)
        HALFSTEP(c + 1, gB, gA, 8)
    }
    HALFSTEP(16, gA, gB, 8)
    HALFSTEP(17, gB, gA, 0)
#undef HALFSTEP

    // partial write: part[half][b][o][p], f32, no bias
    float* pd = part + (((size_t)((half << 2) + b)) << 20);
#pragma unroll
    for (int i = 0; i < 4; ++i) {
        int ob = (wo << 6) + (i << 4) + (kg << 2);
#pragma unroll
        for (int j = 0; j < 2; ++j) {
            int p = pix0 + (wp << 5) + (j << 4) + m16;
#pragma unroll
            for (int r = 0; r < 4; ++r) {
                int oo = ob + r;
                pd[(((size_t)oo) << 12) + p] = acc[i][j][r];
            }
        }
    }
}

// ---------------------------------------------------------------------------
// Kernel 4: combine partials + bias: out = part0 + part1 + b_dcn[o].
// grid 2048 x 256 thr, 8 f32/thread.
// ---------------------------------------------------------------------------
__global__ __launch_bounds__(256) void combine_out(
    const float* __restrict__ part, const float* __restrict__ b_dcn,
    float* __restrict__ out) {
    int i = (blockIdx.x * 256 + threadIdx.x) << 3;
    float bias = b_dcn[(i >> 12) & 255];
    const float* p1 = part + ((size_t)4 << 20);
    float4 a0 = *(const float4*)(part + i);
    float4 a1 = *(const float4*)(part + i + 4);
    float4 c0 = *(const float4*)(p1 + i);
    float4 c1 = *(const float4*)(p1 + i + 4);
    float4 r0 = make_float4(a0.x + c0.x + bias, a0.y + c0.y + bias,
                            a0.z + c0.z + bias, a0.w + c0.w + bias);
    float4 r1 = make_float4(a1.x + c1.x + bias, a1.y + c1.y + bias,
                            a1.z + c1.z + bias, a1.w + c1.w + bias);
    *(float4*)(out + i) = r0;
    *(float4*)(out + i + 4) = r1;
}

// ---------------------------------------------------------------------------
extern "C" void kernel_launch(void* const* d_in, const int* in_sizes, int n_in,
                              void* d_out, int out_size, void* d_ws, size_t ws_size,
                              hipStream_t stream) {
    const float* x      = (const float*)d_in[0];
    const float* w_off  = (const float*)d_in[1];
    const float* b_off  = (const float*)d_in[2];
    const float* w_mask = (const float*)d_in[3];
    const float* b_mask = (const float*)d_in[4];
    const float* w_dcn  = (const float*)d_in[5];
    const float* b_dcn  = (const float*)d_in[6];
    float* out = (float*)d_out;

    float* ws = (float*)d_ws;
    float* offmask = ws;                                       //  1.77 MB
    unsigned short* xTh = (unsigned short*)(offmask + (size_t)B_ * NCH_ * HW_); // 8.39 MB
    unsigned short* wTs = xTh + ((size_t)B_ * HW_ * C_);       //  1.18 MB
    unsigned short* wCs = wTs + (size_t)36 * 16384;            //  0.15 MB
    float* part = (float*)(wCs + (size_t)36 * 2048);           // 33.55 MB (2 halves)
    // total ~45 MB of d_ws

    prep_all<<<dim3(4384), dim3(256), 0, stream>>>(x, xTh, w_dcn, w_off, w_mask, wTs, wCs);
    conv_mfma<<<dim3(512), dim3(256), 0, stream>>>(xTh, wCs, b_off, b_mask, offmask);
    dcn_fused<<<dim3(512), dim3(512), 0, stream>>>(xTh, offmask, wTs, part);
    combine_out<<<dim3(2048), dim3(256), 0, stream>>>(part, b_dcn, out);
}